// Round 1
// baseline (1185.806 us; speedup 1.0000x reference)
//
#include <hip/hip_runtime.h>
#include <stdint.h>

#define B_ 8
#define L_ 4096
#define D_ 1024
#define M_ (B_*L_)        // 32768 rows
#define CHUNKS 16
#define TCH (L_/CHUNKS)   // 256

typedef float f32x4 __attribute__((ext_vector_type(4)));
typedef short short8 __attribute__((ext_vector_type(8)));
typedef unsigned short ushort4v __attribute__((ext_vector_type(4)));

static __device__ __forceinline__ unsigned short f2bf(float f) {
  union { float f; unsigned u; } v; v.f = f;
  unsigned r = v.u + 0x7FFFu + ((v.u >> 16) & 1u);   // round-to-nearest-even
  return (unsigned short)(r >> 16);
}

// ---------------------------------------------------------------------------
// GEMM: C[m,e] = sum_d A[m,d] * W[e,d]  (NT form, both operands K-contiguous)
// MODE 0: dual-B gate gemm -> forget/inp epilogue
// MODE 1: single-B output gemm -> y = z + bias
// Tile 128x128, BK=32, 4 waves (2x2 of 64x64), 16x16x32 bf16 MFMA.
// ---------------------------------------------------------------------------
template<int MODE>
__global__ __launch_bounds__(256, 2)
void gemm_kernel(const float* __restrict__ A,   // M x K fp32
                 const float* __restrict__ B0,  // N x K fp32
                 const float* __restrict__ B1,  // N x K fp32 (MODE 0 only)
                 const float* __restrict__ bias0,
                 const float* __restrict__ bias1,
                 float* __restrict__ out0,
                 float* __restrict__ out1)
{
  constexpr int BM = 128, BN = 128, BK = 32;
  __shared__ unsigned short As[BM * BK];
  __shared__ unsigned short Bs0[BN * BK];
  __shared__ unsigned short Bs1[(MODE == 0) ? (BN * BK) : 8];

  const int tid  = threadIdx.x;
  const int lane = tid & 63;
  const int wave = tid >> 6;
  const int wr = wave >> 1;      // wave row (0..1)
  const int wc = wave & 1;       // wave col (0..1)

  const int bm = blockIdx.x * BM;
  const int bn = blockIdx.y * BN;

  f32x4 acc0[4][4] = {};
  f32x4 acc1[(MODE == 0) ? 4 : 1][(MODE == 0) ? 4 : 1] = {};

  const int frow  = lane & 15;
  const int kslot = lane >> 4;                 // 0..3 (8 bf16 each)
  const int xs    = kslot ^ (frow & 3);        // swizzled 16B slot for reads

  // stage one 128x32 fp32 tile -> bf16 LDS (slot-XOR swizzled)
  auto stage = [&](const float* src, unsigned short* dst) {
    #pragma unroll
    for (int p = 0; p < 4; ++p) {
      int g   = p * 256 + tid;        // each group = 4 elements
      int row = g >> 3;               // 8 groups per 32-wide row
      int kq  = (g & 7) << 2;         // 0,4,...,28
      f32x4 v = *(const f32x4*)(src + (size_t)row * D_ + kq);
      ushort4v w;
      w[0] = f2bf(v[0]); w[1] = f2bf(v[1]); w[2] = f2bf(v[2]); w[3] = f2bf(v[3]);
      int byte = kq << 1;                     // linear byte in row (0..56)
      int slot = byte >> 4;
      int sub  = byte & 15;
      int off  = row * 64 + ((slot ^ (row & 3)) << 4) + sub;
      *(ushort4v*)((char*)dst + off) = w;
    }
  };

  for (int k0 = 0; k0 < D_; k0 += BK) {
    stage(A  + (size_t)bm * D_ + k0, As);
    stage(B0 + (size_t)bn * D_ + k0, Bs0);
    if constexpr (MODE == 0) stage(B1 + (size_t)bn * D_ + k0, Bs1);
    __syncthreads();

    short8 af[4], bf0[4], bf1[4];
    #pragma unroll
    for (int i = 0; i < 4; ++i) {
      int ar = wr * 64 + i * 16 + frow;
      af[i]  = *(const short8*)((const char*)As  + ar * 64 + (xs << 4));
      int br = wc * 64 + i * 16 + frow;
      bf0[i] = *(const short8*)((const char*)Bs0 + br * 64 + (xs << 4));
      if constexpr (MODE == 0)
        bf1[i] = *(const short8*)((const char*)Bs1 + br * 64 + (xs << 4));
    }
    #pragma unroll
    for (int i = 0; i < 4; ++i) {
      #pragma unroll
      for (int j = 0; j < 4; ++j) {
        acc0[i][j] = __builtin_amdgcn_mfma_f32_16x16x32_bf16(af[i], bf0[j], acc0[i][j], 0, 0, 0);
        if constexpr (MODE == 0)
          acc1[i][j] = __builtin_amdgcn_mfma_f32_16x16x32_bf16(af[i], bf1[j], acc1[i][j], 0, 0, 0);
      }
    }
    __syncthreads();
  }

  // epilogue: C/D mapping col=lane&15, row=(lane>>4)*4+r  [m89/m91 verified]
  #pragma unroll
  for (int i = 0; i < 4; ++i) {
    #pragma unroll
    for (int j = 0; j < 4; ++j) {
      #pragma unroll
      for (int r = 0; r < 4; ++r) {
        int row = bm + wr * 64 + i * 16 + (lane >> 4) * 4 + r;
        int col = bn + wc * 64 + j * 16 + (lane & 15);
        size_t idx = (size_t)row * D_ + col;
        if constexpr (MODE == 0) {
          float zf  = acc0[i][j][r] + bias0[col];
          float lin = (float)col * (1.0f / (float)(D_ - 1));
          float rem = lin / (1.0f + __expf(-zf));       // sigmoid * lin
          float zi  = acc1[i][j][r] + bias1[col];
          float e2  = __expf(2.0f * zi);
          float th  = 1.0f - 2.0f / (e2 + 1.0f);        // tanh, inf-safe
          out0[idx] = 1.0f - rem;                        // forget
          out1[idx] = th * rem;                          // inp
        } else {
          out0[idx] = acc0[i][j][r] + bias0[col];        // y
        }
      }
    }
  }
}

// ---------------------------------------------------------------------------
// Chunked parallel scan over L:  h_t = f_t * h_{t-1} + i_t
// ---------------------------------------------------------------------------
__global__ __launch_bounds__(256)
void scan_partial(const float* __restrict__ fg, const float* __restrict__ ip,
                  float* __restrict__ Ag, float* __restrict__ Ug)
{
  int blk = blockIdx.x;                  // B_*CHUNKS*4 blocks
  int e   = ((blk & 3) << 8) + threadIdx.x;
  int c   = (blk >> 2) & (CHUNKS - 1);
  int b   = blk >> 6;
  size_t base = ((size_t)b * L_ + (size_t)c * TCH) * D_ + e;
  float a = 1.0f, u = 0.0f;
  for (int t = 0; t < TCH; ++t) {
    float f = fg[base + (size_t)t * D_];
    float i = ip[base + (size_t)t * D_];
    u = fmaf(f, u, i);
    a *= f;
  }
  size_t o = (size_t)(b * CHUNKS + c) * D_ + e;
  Ag[o] = a; Ug[o] = u;
}

__global__ __launch_bounds__(256)
void scan_carry(const float* __restrict__ Ag, const float* __restrict__ Ug,
                const float* __restrict__ hidden, float* __restrict__ Hin)
{
  int gid = blockIdx.x * 256 + threadIdx.x;   // B_*D_ threads
  int b = gid >> 10, e = gid & (D_ - 1);
  float h = hidden[(size_t)b * D_ + e];
  for (int c = 0; c < CHUNKS; ++c) {
    size_t o = (size_t)(b * CHUNKS + c) * D_ + e;
    Hin[o] = h;
    h = fmaf(Ag[o], h, Ug[o]);
  }
}

__global__ __launch_bounds__(256)
void scan_apply(const float* __restrict__ fg, float* __restrict__ h_io,
                const float* __restrict__ Hin)
{
  int blk = blockIdx.x;
  int e   = ((blk & 3) << 8) + threadIdx.x;
  int c   = (blk >> 2) & (CHUNKS - 1);
  int b   = blk >> 6;
  size_t base = ((size_t)b * L_ + (size_t)c * TCH) * D_ + e;
  float h = Hin[(size_t)(b * CHUNKS + c) * D_ + e];
  for (int t = 0; t < TCH; ++t) {
    size_t o = base + (size_t)t * D_;
    float f = fg[o];
    float i = h_io[o];     // inp, overwritten below
    h = fmaf(f, h, i);
    h_io[o] = h;
  }
}

// ---------------------------------------------------------------------------
extern "C" void kernel_launch(void* const* d_in, const int* in_sizes, int n_in,
                              void* d_out, int out_size, void* d_ws, size_t ws_size,
                              hipStream_t stream)
{
  const float* x      = (const float*)d_in[0];
  const float* hidden = (const float*)d_in[1];
  const float* W_f    = (const float*)d_in[2];
  const float* b_f    = (const float*)d_in[3];
  const float* W_i    = (const float*)d_in[4];
  const float* b_i    = (const float*)d_in[5];
  const float* W_o    = (const float*)d_in[6];
  const float* b_o    = (const float*)d_in[7];

  float* y = (float*)d_out;                 // y region; holds forget during scan
  float* h = y + (size_t)M_ * D_;           // h region; holds inp, then h

  float* Ag  = (float*)d_ws;                          // B*CHUNKS*D each
  float* Ug  = Ag + (size_t)B_ * CHUNKS * D_;
  float* Hin = Ug + (size_t)B_ * CHUNKS * D_;

  dim3 gg(M_ / 128, D_ / 128);
  gemm_kernel<0><<<gg, 256, 0, stream>>>(x, W_f, W_i, b_f, b_i, y, h);

  int pblocks = B_ * CHUNKS * (D_ / 256);
  scan_partial<<<pblocks, 256, 0, stream>>>(y, h, Ag, Ug);
  scan_carry<<<(B_ * D_) / 256, 256, 0, stream>>>(Ag, Ug, hidden, Hin);
  scan_apply<<<pblocks, 256, 0, stream>>>(y, h, Hin);

  gemm_kernel<1><<<gg, 256, 0, stream>>>(h, W_o, nullptr, b_o, nullptr, y, nullptr);
}

// Round 2
// 683.172 us; speedup vs baseline: 1.7357x; 1.7357x over previous
//
#include <hip/hip_runtime.h>
#include <stdint.h>

#define B_ 8
#define L_ 4096
#define D_ 1024
#define M_ (B_*L_)        // 32768 rows
#define CHUNKS 32
#define TCH (L_/CHUNKS)   // 128

typedef float f32x4 __attribute__((ext_vector_type(4)));
typedef float f32x2 __attribute__((ext_vector_type(2)));
typedef short short8 __attribute__((ext_vector_type(8)));
typedef unsigned short ushort4v __attribute__((ext_vector_type(4)));

static __device__ __forceinline__ unsigned short f2bf(float f) {
  union { float f; unsigned u; } v; v.f = f;
  unsigned r = v.u + 0x7FFFu + ((v.u >> 16) & 1u);   // round-to-nearest-even
  return (unsigned short)(r >> 16);
}

#define GLOAD16(g, l) \
  __builtin_amdgcn_global_load_lds((__attribute__((address_space(1))) const void*)(g), \
                                   (__attribute__((address_space(3))) void*)(l), 16, 0, 0)

// ---------------------------------------------------------------------------
// fp32 -> bf16 convert, 8 elems/thread
// ---------------------------------------------------------------------------
__global__ __launch_bounds__(256)
void cvt_bf16(const float* __restrict__ src, unsigned short* __restrict__ dst, int n8)
{
  int gid = blockIdx.x * 256 + threadIdx.x;
  if (gid >= n8) return;
  const f32x4* s = (const f32x4*)(src + (size_t)gid * 8);
  f32x4 v0 = s[0], v1 = s[1];
  union { short8 v; unsigned short u[8]; } w;
  w.u[0] = f2bf(v0[0]); w.u[1] = f2bf(v0[1]); w.u[2] = f2bf(v0[2]); w.u[3] = f2bf(v0[3]);
  w.u[4] = f2bf(v1[0]); w.u[5] = f2bf(v1[1]); w.u[6] = f2bf(v1[2]); w.u[7] = f2bf(v1[3]);
  *(short8*)(dst + (size_t)gid * 8) = w.v;
}

// ---------------------------------------------------------------------------
// Fast GEMM (m97 structure): bf16 in, global_load_lds staging, 128x128 tile,
// BK=32, 4 waves (2x2 of 64x64), 16x16x32 bf16 MFMA.
// C[m,e] = sum_d A[m,d]*W[e,d]  (NT: both K-contiguous)
// MODE 0: dual-B gate gemm -> forget/inp epilogue.  MODE 1: y = z + bias.
// ---------------------------------------------------------------------------
template<int MODE>
__global__ __launch_bounds__(256)
void gemm_fast(const unsigned short* __restrict__ A,
               const unsigned short* __restrict__ B0,
               const unsigned short* __restrict__ B1,
               const float* __restrict__ bias0,
               const float* __restrict__ bias1,
               float* __restrict__ out0,
               float* __restrict__ out1)
{
  constexpr int BK = 32;
  __shared__ unsigned short As [128 * BK];
  __shared__ unsigned short Bs0[128 * BK];
  __shared__ unsigned short Bs1[(MODE == 0) ? (128 * BK) : 8];

  const int tid  = threadIdx.x;
  const int lane = tid & 63;
  const int wave = tid >> 6;
  const int wr = wave >> 1, wc = wave & 1;
  const int bm = blockIdx.x * 128, bn = blockIdx.y * 128;
  const int frow = lane & 15, ks = lane >> 4;

  f32x4 acc0[4][4] = {};
  f32x4 acc1[(MODE == 0) ? 4 : 1][(MODE == 0) ? 4 : 1] = {};

  const char* Abase  = (const char*)A  + (size_t)bm * 2048;   // 2048 B per row (D_ bf16)
  const char* B0base = (const char*)B0 + (size_t)bn * 2048;
  const char* B1base = (MODE == 0) ? ((const char*)B1 + (size_t)bn * 2048) : nullptr;

  // staging: tile 128x32 bf16 = 8192 B; 256 thr x 16 B = 4096 B/inst -> 2 inst
  const int so0 = tid * 16;
  const int r0 = so0 >> 6, c0 = so0 & 63;
  const int so1 = so0 + 4096;
  const int r1 = so1 >> 6, c1 = so1 & 63;

  for (int k0 = 0; k0 < D_; k0 += BK) {
    size_t g0 = (size_t)r0 * 2048 + (size_t)(k0 * 2) + c0;
    size_t g1 = (size_t)r1 * 2048 + (size_t)(k0 * 2) + c1;
    GLOAD16(Abase  + g0, (char*)As  + so0);
    GLOAD16(Abase  + g1, (char*)As  + so1);
    GLOAD16(B0base + g0, (char*)Bs0 + so0);
    GLOAD16(B0base + g1, (char*)Bs0 + so1);
    if constexpr (MODE == 0) {
      GLOAD16(B1base + g0, (char*)Bs1 + so0);
      GLOAD16(B1base + g1, (char*)Bs1 + so1);
    }
    __syncthreads();

    short8 af[4], bf0[4], bf1[4];
    #pragma unroll
    for (int i = 0; i < 4; ++i) {
      int ar = wr * 64 + i * 16 + frow;
      af[i]  = *(const short8*)((const char*)As  + ar * 64 + (ks << 4));
      int br = wc * 64 + i * 16 + frow;
      bf0[i] = *(const short8*)((const char*)Bs0 + br * 64 + (ks << 4));
      if constexpr (MODE == 0)
        bf1[i] = *(const short8*)((const char*)Bs1 + br * 64 + (ks << 4));
    }
    #pragma unroll
    for (int i = 0; i < 4; ++i) {
      #pragma unroll
      for (int j = 0; j < 4; ++j) {
        acc0[i][j] = __builtin_amdgcn_mfma_f32_16x16x32_bf16(af[i], bf0[j], acc0[i][j], 0, 0, 0);
        if constexpr (MODE == 0)
          acc1[i][j] = __builtin_amdgcn_mfma_f32_16x16x32_bf16(af[i], bf1[j], acc1[i][j], 0, 0, 0);
      }
    }
    __syncthreads();
  }

  // epilogue: C/D mapping col=lane&15, row=(lane>>4)*4+r  [m89/m91 verified]
  #pragma unroll
  for (int i = 0; i < 4; ++i) {
    #pragma unroll
    for (int j = 0; j < 4; ++j) {
      #pragma unroll
      for (int r = 0; r < 4; ++r) {
        int row = bm + wr * 64 + i * 16 + (lane >> 4) * 4 + r;
        int col = bn + wc * 64 + j * 16 + (lane & 15);
        size_t idx = (size_t)row * D_ + col;
        if constexpr (MODE == 0) {
          float zf  = acc0[i][j][r] + bias0[col];
          float lin = (float)col * (1.0f / (float)(D_ - 1));
          float rem = lin / (1.0f + __expf(-zf));       // sigmoid * lin
          float zi  = acc1[i][j][r] + bias1[col];
          float e2  = __expf(2.0f * zi);
          float th  = 1.0f - 2.0f / (e2 + 1.0f);        // tanh, inf-safe
          out0[idx] = 1.0f - rem;                        // forget
          out1[idx] = th * rem;                          // inp
        } else {
          out0[idx] = acc0[i][j][r] + bias0[col];        // y
        }
      }
    }
  }
}

// ---------------------------------------------------------------------------
// Slow fallback GEMM (round-1 path, fp32 in, reg-staged convert) — used only
// if ws_size is too small for the bf16 scratch.
// ---------------------------------------------------------------------------
template<int MODE>
__global__ __launch_bounds__(256, 2)
void gemm_slow(const float* __restrict__ A, const float* __restrict__ B0,
               const float* __restrict__ B1, const float* __restrict__ bias0,
               const float* __restrict__ bias1, float* __restrict__ out0,
               float* __restrict__ out1)
{
  constexpr int BK = 32;
  __shared__ unsigned short As[128 * BK];
  __shared__ unsigned short Bs0[128 * BK];
  __shared__ unsigned short Bs1[(MODE == 0) ? (128 * BK) : 8];

  const int tid = threadIdx.x, lane = tid & 63, wave = tid >> 6;
  const int wr = wave >> 1, wc = wave & 1;
  const int bm = blockIdx.x * 128, bn = blockIdx.y * 128;
  f32x4 acc0[4][4] = {};
  f32x4 acc1[(MODE == 0) ? 4 : 1][(MODE == 0) ? 4 : 1] = {};
  const int frow = lane & 15, kslot = lane >> 4;
  const int xs = kslot ^ (frow & 3);

  auto stage = [&](const float* src, unsigned short* dst) {
    #pragma unroll
    for (int p = 0; p < 4; ++p) {
      int g = p * 256 + tid;
      int row = g >> 3, kq = (g & 7) << 2;
      f32x4 v = *(const f32x4*)(src + (size_t)row * D_ + kq);
      ushort4v w;
      w[0] = f2bf(v[0]); w[1] = f2bf(v[1]); w[2] = f2bf(v[2]); w[3] = f2bf(v[3]);
      int byte = kq << 1, slot = byte >> 4, sub = byte & 15;
      int off = row * 64 + ((slot ^ (row & 3)) << 4) + sub;
      *(ushort4v*)((char*)dst + off) = w;
    }
  };

  for (int k0 = 0; k0 < D_; k0 += BK) {
    stage(A + (size_t)bm * D_ + k0, As);
    stage(B0 + (size_t)bn * D_ + k0, Bs0);
    if constexpr (MODE == 0) stage(B1 + (size_t)bn * D_ + k0, Bs1);
    __syncthreads();
    short8 af[4], bf0[4], bf1[4];
    #pragma unroll
    for (int i = 0; i < 4; ++i) {
      int ar = wr * 64 + i * 16 + frow;
      af[i] = *(const short8*)((const char*)As + ar * 64 + (xs << 4));
      int br = wc * 64 + i * 16 + frow;
      bf0[i] = *(const short8*)((const char*)Bs0 + br * 64 + (xs << 4));
      if constexpr (MODE == 0)
        bf1[i] = *(const short8*)((const char*)Bs1 + br * 64 + (xs << 4));
    }
    #pragma unroll
    for (int i = 0; i < 4; ++i)
      #pragma unroll
      for (int j = 0; j < 4; ++j) {
        acc0[i][j] = __builtin_amdgcn_mfma_f32_16x16x32_bf16(af[i], bf0[j], acc0[i][j], 0, 0, 0);
        if constexpr (MODE == 0)
          acc1[i][j] = __builtin_amdgcn_mfma_f32_16x16x32_bf16(af[i], bf1[j], acc1[i][j], 0, 0, 0);
      }
    __syncthreads();
  }
  #pragma unroll
  for (int i = 0; i < 4; ++i)
    #pragma unroll
    for (int j = 0; j < 4; ++j)
      #pragma unroll
      for (int r = 0; r < 4; ++r) {
        int row = bm + wr * 64 + i * 16 + (lane >> 4) * 4 + r;
        int col = bn + wc * 64 + j * 16 + (lane & 15);
        size_t idx = (size_t)row * D_ + col;
        if constexpr (MODE == 0) {
          float zf = acc0[i][j][r] + bias0[col];
          float lin = (float)col * (1.0f / (float)(D_ - 1));
          float rem = lin / (1.0f + __expf(-zf));
          float zi = acc1[i][j][r] + bias1[col];
          float e2 = __expf(2.0f * zi);
          float th = 1.0f - 2.0f / (e2 + 1.0f);
          out0[idx] = 1.0f - rem;
          out1[idx] = th * rem;
        } else {
          out0[idx] = acc0[i][j][r] + bias0[col];
        }
      }
}

// ---------------------------------------------------------------------------
// Chunked parallel scan over L:  h_t = f_t * h_{t-1} + i_t   (float2 lanes)
// ---------------------------------------------------------------------------
__global__ __launch_bounds__(256)
void scan_partial(const float* __restrict__ fg, const float* __restrict__ ip,
                  float* __restrict__ Ag, float* __restrict__ Ug)
{
  int blk = blockIdx.x;                      // B_*CHUNKS*2 blocks
  int b = blk >> 6;
  int c = (blk >> 1) & (CHUNKS - 1);
  int e = ((blk & 1) << 9) + threadIdx.x * 2;
  size_t base = ((size_t)b * L_ + (size_t)c * TCH) * D_ + e;
  f32x2 a = {1.0f, 1.0f}, u = {0.0f, 0.0f};
  for (int t = 0; t < TCH; ++t) {
    f32x2 f = *(const f32x2*)(fg + base + (size_t)t * D_);
    f32x2 i = *(const f32x2*)(ip + base + (size_t)t * D_);
    u = f * u + i;
    a = a * f;
  }
  size_t o = (size_t)(b * CHUNKS + c) * D_ + e;
  *(f32x2*)(Ag + o) = a;
  *(f32x2*)(Ug + o) = u;
}

__global__ __launch_bounds__(256)
void scan_carry(const float* __restrict__ Ag, const float* __restrict__ Ug,
                const float* __restrict__ hidden, float* __restrict__ Hin)
{
  int gid = blockIdx.x * 256 + threadIdx.x;  // B_*D_/2 threads
  int b = gid >> 9;
  int e = (gid & 511) * 2;
  f32x2 h = *(const f32x2*)(hidden + (size_t)b * D_ + e);
  for (int c = 0; c < CHUNKS; ++c) {
    size_t o = (size_t)(b * CHUNKS + c) * D_ + e;
    *(f32x2*)(Hin + o) = h;
    f32x2 A = *(const f32x2*)(Ag + o);
    f32x2 U = *(const f32x2*)(Ug + o);
    h = A * h + U;
  }
}

template<int WB>   // WB=1: also emit bf16 h into hb
__global__ __launch_bounds__(256)
void scan_apply(const float* __restrict__ fg, float* __restrict__ h_io,
                const float* __restrict__ Hin, unsigned short* __restrict__ hb)
{
  int blk = blockIdx.x;
  int b = blk >> 6;
  int c = (blk >> 1) & (CHUNKS - 1);
  int e = ((blk & 1) << 9) + threadIdx.x * 2;
  size_t base = ((size_t)b * L_ + (size_t)c * TCH) * D_ + e;
  f32x2 h = *(const f32x2*)(Hin + (size_t)(b * CHUNKS + c) * D_ + e);
  for (int t = 0; t < TCH; ++t) {
    size_t o = base + (size_t)t * D_;
    f32x2 f = *(const f32x2*)(fg + o);
    f32x2 i = *(const f32x2*)(h_io + o);
    h = f * h + i;
    *(f32x2*)(h_io + o) = h;
    if constexpr (WB) {
      unsigned pack = (unsigned)f2bf(h[0]) | ((unsigned)f2bf(h[1]) << 16);
      *(unsigned*)(hb + o) = pack;
    }
  }
}

// ---------------------------------------------------------------------------
extern "C" void kernel_launch(void* const* d_in, const int* in_sizes, int n_in,
                              void* d_out, int out_size, void* d_ws, size_t ws_size,
                              hipStream_t stream)
{
  const float* x      = (const float*)d_in[0];
  const float* hidden = (const float*)d_in[1];
  const float* W_f    = (const float*)d_in[2];
  const float* b_f    = (const float*)d_in[3];
  const float* W_i    = (const float*)d_in[4];
  const float* b_i    = (const float*)d_in[5];
  const float* W_o    = (const float*)d_in[6];
  const float* b_o    = (const float*)d_in[7];

  float* y = (float*)d_out;                 // y region; holds forget during scan
  float* h = y + (size_t)M_ * D_;           // h region; holds inp, then h

  const size_t xb_elems = (size_t)M_ * D_;
  const size_t w_elems  = (size_t)D_ * D_;
  const size_t agg      = (size_t)B_ * CHUNKS * D_;
  const size_t need = (xb_elems + 3 * w_elems) * 2 + agg * 3 * 4;

  dim3 gg(M_ / 128, D_ / 128);
  int pblocks = B_ * CHUNKS * 2;
  int cblocks = (B_ * D_ / 2) / 256;

  if (ws_size >= need) {
    unsigned short* xb  = (unsigned short*)d_ws;
    unsigned short* wfb = xb + xb_elems;
    unsigned short* wib = wfb + w_elems;
    unsigned short* wob = wib + w_elems;
    float* Ag  = (float*)(wob + w_elems);
    float* Ug  = Ag + agg;
    float* Hin = Ug + agg;

    cvt_bf16<<<(int)(xb_elems / 8 / 256), 256, 0, stream>>>(x,   xb,  (int)(xb_elems / 8));
    cvt_bf16<<<(int)(w_elems / 8 / 256), 256, 0, stream>>>(W_f, wfb, (int)(w_elems / 8));
    cvt_bf16<<<(int)(w_elems / 8 / 256), 256, 0, stream>>>(W_i, wib, (int)(w_elems / 8));
    cvt_bf16<<<(int)(w_elems / 8 / 256), 256, 0, stream>>>(W_o, wob, (int)(w_elems / 8));

    gemm_fast<0><<<gg, 256, 0, stream>>>(xb, wfb, wib, b_f, b_i, y, h);

    scan_partial<<<pblocks, 256, 0, stream>>>(y, h, Ag, Ug);
    scan_carry<<<cblocks, 256, 0, stream>>>(Ag, Ug, hidden, Hin);
    scan_apply<1><<<pblocks, 256, 0, stream>>>(y, h, Hin, xb);  // xb now holds bf16 h

    gemm_fast<1><<<gg, 256, 0, stream>>>(xb, wob, nullptr, b_o, nullptr, y, nullptr);
  } else {
    float* Ag  = (float*)d_ws;
    float* Ug  = Ag + agg;
    float* Hin = Ug + agg;

    gemm_slow<0><<<gg, 256, 0, stream>>>(x, W_f, W_i, b_f, b_i, y, h);
    scan_partial<<<pblocks, 256, 0, stream>>>(y, h, Ag, Ug);
    scan_carry<<<cblocks, 256, 0, stream>>>(Ag, Ug, hidden, Hin);
    scan_apply<0><<<pblocks, 256, 0, stream>>>(y, h, Hin, nullptr);
    gemm_slow<1><<<gg, 256, 0, stream>>>(h, W_o, nullptr, b_o, nullptr, y, nullptr);
  }
}

// Round 3
// 520.636 us; speedup vs baseline: 2.2776x; 1.3122x over previous
//
#include <hip/hip_runtime.h>
#include <stdint.h>

#define B_ 8
#define L_ 4096
#define D_ 1024
#define M_ (B_*L_)        // 32768 rows
#define CHUNKS 32
#define TCH (L_/CHUNKS)   // 128

typedef float f32x4 __attribute__((ext_vector_type(4)));
typedef float f32x2 __attribute__((ext_vector_type(2)));
typedef short short8 __attribute__((ext_vector_type(8)));
typedef unsigned short ushort4v __attribute__((ext_vector_type(4)));

static __device__ __forceinline__ unsigned short f2bf(float f) {
  union { float f; unsigned u; } v; v.f = f;
  unsigned r = v.u + 0x7FFFu + ((v.u >> 16) & 1u);   // round-to-nearest-even
  return (unsigned short)(r >> 16);
}

#define GLOAD16(g, l) \
  __builtin_amdgcn_global_load_lds((__attribute__((address_space(1))) const void*)(g), \
                                   (__attribute__((address_space(3))) void*)(l), 16, 0, 0)

// ---------------------------------------------------------------------------
// fp32 -> bf16 convert, 8 elems/thread
// ---------------------------------------------------------------------------
__global__ __launch_bounds__(256)
void cvt_bf16(const float* __restrict__ src, unsigned short* __restrict__ dst, int n8)
{
  int gid = blockIdx.x * 256 + threadIdx.x;
  if (gid >= n8) return;
  const f32x4* s = (const f32x4*)(src + (size_t)gid * 8);
  f32x4 v0 = s[0], v1 = s[1];
  union { short8 v; unsigned short u[8]; } w;
  w.u[0] = f2bf(v0[0]); w.u[1] = f2bf(v0[1]); w.u[2] = f2bf(v0[2]); w.u[3] = f2bf(v0[3]);
  w.u[4] = f2bf(v1[0]); w.u[5] = f2bf(v1[1]); w.u[6] = f2bf(v1[2]); w.u[7] = f2bf(v1[3]);
  *(short8*)(dst + (size_t)gid * 8) = w.v;
}

// ---------------------------------------------------------------------------
// Single-B GEMM, 2-phase double-buffered pipeline.
// C[m,e] = sum_d A[m,d]*W[e,d] + bias[e]   (NT; M=32768, N=1024, K=1024)
// 128x128 tile, BK=32, 4 waves (2x2 of 64x64), 16x16x32 bf16 MFMA.
// LDS read-swizzle slot^=(row>>1)&3, realized by pre-swizzling the
// global_load_lds SOURCE address (LDS dest stays linear — rule 21).
// ---------------------------------------------------------------------------
__global__ __launch_bounds__(256, 4)
void gemm_nt(const unsigned short* __restrict__ A,
             const unsigned short* __restrict__ Bw,
             const float* __restrict__ bias,
             float* __restrict__ out)
{
  __shared__ unsigned short As[2][4096];   // 2 x 8KB
  __shared__ unsigned short Bs[2][4096];

  const int tid  = threadIdx.x;
  const int lane = tid & 63;
  const int wave = tid >> 6;
  const int wr = wave >> 1, wc = wave & 1;
  const int frow = lane & 15, ks = lane >> 4;
  const int xslot = (ks ^ ((frow >> 1) & 3)) << 4;   // swizzled 16B slot (bytes)

  // XCD-bijective swizzle (nwg % 8 == 0), bn fastest within an XCD chunk
  const int nwg = gridDim.x;
  const int wg  = (blockIdx.x & 7) * (nwg >> 3) + (blockIdx.x >> 3);
  const int bm  = (wg >> 3) * 128;
  const int bn  = (wg & 7) * 128;

  // staging geometry: 128x32 bf16 tile = 8KB, 2 gload16/thread per matrix
  const int so   = tid * 16;                           // linear LDS dest
  const int srow = tid >> 2;                           // 0..63
  const int g16  = ((tid & 3) ^ ((tid >> 3) & 3)) << 4; // pre-swizzled slot

  const char* pA0 = (const char*)A  + (size_t)(bm + srow) * 2048 + g16;
  const char* pA1 = pA0 + (size_t)64 * 2048;
  const char* pB0 = (const char*)Bw + (size_t)(bn + srow) * 2048 + g16;
  const char* pB1 = pB0 + (size_t)64 * 2048;

  f32x4 acc[4][4] = {};

  auto stage = [&](int kb, int bb) {
    GLOAD16(pA0 + kb, (char*)As[bb] + so);
    GLOAD16(pA1 + kb, (char*)As[bb] + so + 4096);
    GLOAD16(pB0 + kb, (char*)Bs[bb] + so);
    GLOAD16(pB1 + kb, (char*)Bs[bb] + so + 4096);
  };

  stage(0, 0);
  __syncthreads();
  int cur = 0;
  for (int k = 0; k < 32; ++k) {
    if (k < 31) stage((k + 1) * 64, cur ^ 1);          // prefetch next tile
    short8 af[4], bf[4];
    #pragma unroll
    for (int i = 0; i < 4; ++i) {
      int ar = wr * 64 + i * 16 + frow;
      af[i] = *(const short8*)((const char*)As[cur] + ar * 64 + xslot);
      int br = wc * 64 + i * 16 + frow;
      bf[i] = *(const short8*)((const char*)Bs[cur] + br * 64 + xslot);
    }
    #pragma unroll
    for (int i = 0; i < 4; ++i)
      #pragma unroll
      for (int j = 0; j < 4; ++j)
        acc[i][j] = __builtin_amdgcn_mfma_f32_16x16x32_bf16(af[i], bf[j], acc[i][j], 0, 0, 0);
    __syncthreads();                                    // drains prefetch too
    cur ^= 1;
  }

  float bv[4];
  #pragma unroll
  for (int j = 0; j < 4; ++j) bv[j] = bias[bn + wc * 64 + j * 16 + frow];
  #pragma unroll
  for (int i = 0; i < 4; ++i) {
    int row = bm + wr * 64 + i * 16 + ks * 4;
    #pragma unroll
    for (int j = 0; j < 4; ++j) {
      int col = bn + wc * 64 + j * 16 + frow;
      #pragma unroll
      for (int r = 0; r < 4; ++r)
        out[(size_t)(row + r) * D_ + col] = acc[i][j][r] + bv[j];
    }
  }
}

// ---------------------------------------------------------------------------
// Gate transform: (zf, zi, lin) -> (f, inp)
// ---------------------------------------------------------------------------
static __device__ __forceinline__ void gate2(f32x2 zf, f32x2 zi, f32x2 lin,
                                             f32x2& f, f32x2& inp)
{
  f32x2 rem, th;
  rem[0] = lin[0] / (1.0f + __expf(-zf[0]));
  rem[1] = lin[1] / (1.0f + __expf(-zf[1]));
  float e0 = __expf(2.0f * zi[0]);
  float e1 = __expf(2.0f * zi[1]);
  th[0] = 1.0f - 2.0f / (e0 + 1.0f);
  th[1] = 1.0f - 2.0f / (e1 + 1.0f);
  f[0] = 1.0f - rem[0]; f[1] = 1.0f - rem[1];
  inp = th * rem;
}

// ---------------------------------------------------------------------------
// Chunked parallel scan over L:  h_t = f_t * h_{t-1} + i_t   (float2 lanes)
// GATED=1: p0/p1 hold raw zf/zi, gates computed on the fly.
// ---------------------------------------------------------------------------
template<int GATED>
__global__ __launch_bounds__(256)
void scan_partial(const float* __restrict__ p0, const float* __restrict__ p1,
                  float* __restrict__ Ag, float* __restrict__ Ug)
{
  int blk = blockIdx.x;                      // B_*CHUNKS*2 blocks
  int b = blk >> 6;
  int c = (blk >> 1) & (CHUNKS - 1);
  int e = ((blk & 1) << 9) + threadIdx.x * 2;
  f32x2 lin; lin[0] = (float)e * (1.0f/1023.0f); lin[1] = (float)(e+1) * (1.0f/1023.0f);
  size_t base = ((size_t)b * L_ + (size_t)c * TCH) * D_ + e;
  f32x2 a = {1.0f, 1.0f}, u = {0.0f, 0.0f};
  for (int t = 0; t < TCH; ++t) {
    f32x2 v0 = *(const f32x2*)(p0 + base + (size_t)t * D_);
    f32x2 v1 = *(const f32x2*)(p1 + base + (size_t)t * D_);
    f32x2 f, inp;
    if constexpr (GATED) gate2(v0, v1, lin, f, inp);
    else { f = v0; inp = v1; }
    u = f * u + inp;
    a = a * f;
  }
  size_t o = (size_t)(b * CHUNKS + c) * D_ + e;
  *(f32x2*)(Ag + o) = a;
  *(f32x2*)(Ug + o) = u;
}

__global__ __launch_bounds__(256)
void scan_carry(const float* __restrict__ Ag, const float* __restrict__ Ug,
                const float* __restrict__ hidden, float* __restrict__ Hin)
{
  int gid = blockIdx.x * 256 + threadIdx.x;  // B_*D_/2 threads
  int b = gid >> 9;
  int e = (gid & 511) * 2;
  f32x2 h = *(const f32x2*)(hidden + (size_t)b * D_ + e);
  for (int c = 0; c < CHUNKS; ++c) {
    size_t o = (size_t)(b * CHUNKS + c) * D_ + e;
    *(f32x2*)(Hin + o) = h;
    f32x2 A = *(const f32x2*)(Ag + o);
    f32x2 U = *(const f32x2*)(Ug + o);
    h = A * h + U;
  }
}

template<int GATED, int WB>   // WB=1: also emit bf16 h into hb
__global__ __launch_bounds__(256)
void scan_apply(const float* __restrict__ p0, float* __restrict__ p1_io,
                const float* __restrict__ Hin, unsigned short* __restrict__ hb)
{
  int blk = blockIdx.x;
  int b = blk >> 6;
  int c = (blk >> 1) & (CHUNKS - 1);
  int e = ((blk & 1) << 9) + threadIdx.x * 2;
  f32x2 lin; lin[0] = (float)e * (1.0f/1023.0f); lin[1] = (float)(e+1) * (1.0f/1023.0f);
  size_t base = ((size_t)b * L_ + (size_t)c * TCH) * D_ + e;
  f32x2 h = *(const f32x2*)(Hin + (size_t)(b * CHUNKS + c) * D_ + e);
  for (int t = 0; t < TCH; ++t) {
    size_t o = base + (size_t)t * D_;
    f32x2 v0 = *(const f32x2*)(p0 + o);
    f32x2 v1 = *(const f32x2*)(p1_io + o);
    f32x2 f, inp;
    if constexpr (GATED) gate2(v0, v1, lin, f, inp);
    else { f = v0; inp = v1; }
    h = f * h + inp;
    *(f32x2*)(p1_io + o) = h;
    if constexpr (WB) {
      unsigned pack = (unsigned)f2bf(h[0]) | ((unsigned)f2bf(h[1]) << 16);
      *(unsigned*)(hb + o) = pack;
    }
  }
}

// ---------------------------------------------------------------------------
// Slow fallback GEMM (fp32 in, reg-staged convert) — only if ws too small.
// ---------------------------------------------------------------------------
template<int MODE>
__global__ __launch_bounds__(256, 2)
void gemm_slow(const float* __restrict__ A, const float* __restrict__ B0,
               const float* __restrict__ B1, const float* __restrict__ bias0,
               const float* __restrict__ bias1, float* __restrict__ out0,
               float* __restrict__ out1)
{
  constexpr int BK = 32;
  __shared__ unsigned short As[128 * BK];
  __shared__ unsigned short Bs0[128 * BK];
  __shared__ unsigned short Bs1[(MODE == 0) ? (128 * BK) : 8];

  const int tid = threadIdx.x, lane = tid & 63, wave = tid >> 6;
  const int wr = wave >> 1, wc = wave & 1;
  const int bm = blockIdx.x * 128, bn = blockIdx.y * 128;
  f32x4 acc0[4][4] = {};
  f32x4 acc1[(MODE == 0) ? 4 : 1][(MODE == 0) ? 4 : 1] = {};
  const int frow = lane & 15, kslot = lane >> 4;
  const int xs = kslot ^ (frow & 3);

  auto stage = [&](const float* src, unsigned short* dst) {
    #pragma unroll
    for (int p = 0; p < 4; ++p) {
      int g = p * 256 + tid;
      int row = g >> 3, kq = (g & 7) << 2;
      f32x4 v = *(const f32x4*)(src + (size_t)row * D_ + kq);
      ushort4v w;
      w[0] = f2bf(v[0]); w[1] = f2bf(v[1]); w[2] = f2bf(v[2]); w[3] = f2bf(v[3]);
      int byte = kq << 1, slot = byte >> 4, sub = byte & 15;
      int off = row * 64 + ((slot ^ (row & 3)) << 4) + sub;
      *(ushort4v*)((char*)dst + off) = w;
    }
  };

  for (int k0 = 0; k0 < D_; k0 += BK) {
    stage(A + (size_t)bm * D_ + k0, As);
    stage(B0 + (size_t)bn * D_ + k0, Bs0);
    if constexpr (MODE == 0) stage(B1 + (size_t)bn * D_ + k0, Bs1);
    __syncthreads();
    short8 af[4], bf0[4], bf1[4];
    #pragma unroll
    for (int i = 0; i < 4; ++i) {
      int ar = wr * 64 + i * 16 + frow;
      af[i] = *(const short8*)((const char*)As + ar * 64 + (xs << 4));
      int br = wc * 64 + i * 16 + frow;
      bf0[i] = *(const short8*)((const char*)Bs0 + br * 64 + (xs << 4));
      if constexpr (MODE == 0)
        bf1[i] = *(const short8*)((const char*)Bs1 + br * 64 + (xs << 4));
    }
    #pragma unroll
    for (int i = 0; i < 4; ++i)
      #pragma unroll
      for (int j = 0; j < 4; ++j) {
        acc0[i][j] = __builtin_amdgcn_mfma_f32_16x16x32_bf16(af[i], bf0[j], acc0[i][j], 0, 0, 0);
        if constexpr (MODE == 0)
          acc1[i][j] = __builtin_amdgcn_mfma_f32_16x16x32_bf16(af[i], bf1[j], acc1[i][j], 0, 0, 0);
      }
    __syncthreads();
  }
  #pragma unroll
  for (int i = 0; i < 4; ++i)
    #pragma unroll
    for (int j = 0; j < 4; ++j)
      #pragma unroll
      for (int r = 0; r < 4; ++r) {
        int row = bm + wr * 64 + i * 16 + (lane >> 4) * 4 + r;
        int col = bn + wc * 64 + j * 16 + (lane & 15);
        size_t idx = (size_t)row * D_ + col;
        if constexpr (MODE == 0) {
          float zf = acc0[i][j][r] + bias0[col];
          float linv = (float)col * (1.0f / 1023.0f);
          float rem = linv / (1.0f + __expf(-zf));
          float zi = acc1[i][j][r] + bias1[col];
          float e2 = __expf(2.0f * zi);
          float th = 1.0f - 2.0f / (e2 + 1.0f);
          out0[idx] = 1.0f - rem;
          out1[idx] = th * rem;
        } else {
          out0[idx] = acc0[i][j][r] + bias0[col];
        }
      }
}

// ---------------------------------------------------------------------------
extern "C" void kernel_launch(void* const* d_in, const int* in_sizes, int n_in,
                              void* d_out, int out_size, void* d_ws, size_t ws_size,
                              hipStream_t stream)
{
  const float* x      = (const float*)d_in[0];
  const float* hidden = (const float*)d_in[1];
  const float* W_f    = (const float*)d_in[2];
  const float* b_f    = (const float*)d_in[3];
  const float* W_i    = (const float*)d_in[4];
  const float* b_i    = (const float*)d_in[5];
  const float* W_o    = (const float*)d_in[6];
  const float* b_o    = (const float*)d_in[7];

  float* y = (float*)d_out;                 // holds zf during scan, then y
  float* h = y + (size_t)M_ * D_;           // holds zi, then h

  const size_t xb_elems = (size_t)M_ * D_;
  const size_t w_elems  = (size_t)D_ * D_;
  const size_t agg      = (size_t)B_ * CHUNKS * D_;
  const size_t need = (xb_elems + 3 * w_elems) * 2 + agg * 3 * 4;

  int pblocks = B_ * CHUNKS * 2;
  int cblocks = (B_ * D_ / 2) / 256;

  if (ws_size >= need) {
    unsigned short* xb  = (unsigned short*)d_ws;
    unsigned short* wfb = xb + xb_elems;
    unsigned short* wib = wfb + w_elems;
    unsigned short* wob = wib + w_elems;
    float* Ag  = (float*)(wob + w_elems);
    float* Ug  = Ag + agg;
    float* Hin = Ug + agg;

    cvt_bf16<<<(int)(xb_elems / 8 / 256), 256, 0, stream>>>(x,   xb,  (int)(xb_elems / 8));
    cvt_bf16<<<(int)(w_elems / 8 / 256), 256, 0, stream>>>(W_f, wfb, (int)(w_elems / 8));
    cvt_bf16<<<(int)(w_elems / 8 / 256), 256, 0, stream>>>(W_i, wib, (int)(w_elems / 8));
    cvt_bf16<<<(int)(w_elems / 8 / 256), 256, 0, stream>>>(W_o, wob, (int)(w_elems / 8));

    int gblocks = (M_ / 128) * (D_ / 128);   // 2048
    gemm_nt<<<gblocks, 256, 0, stream>>>(xb, wfb, b_f, y);   // zf
    gemm_nt<<<gblocks, 256, 0, stream>>>(xb, wib, b_i, h);   // zi

    scan_partial<1><<<pblocks, 256, 0, stream>>>(y, h, Ag, Ug);
    scan_carry<<<cblocks, 256, 0, stream>>>(Ag, Ug, hidden, Hin);
    scan_apply<1, 1><<<pblocks, 256, 0, stream>>>(y, h, Hin, xb); // h fp32 + bf16

    gemm_nt<<<gblocks, 256, 0, stream>>>(xb, wob, b_o, y);   // y
  } else {
    float* Ag  = (float*)d_ws;
    float* Ug  = Ag + agg;
    float* Hin = Ug + agg;
    dim3 gg(M_ / 128, D_ / 128);

    gemm_slow<0><<<gg, 256, 0, stream>>>(x, W_f, W_i, b_f, b_i, y, h);
    scan_partial<0><<<pblocks, 256, 0, stream>>>(y, h, Ag, Ug);
    scan_carry<<<cblocks, 256, 0, stream>>>(Ag, Ug, hidden, Hin);
    scan_apply<0, 0><<<pblocks, 256, 0, stream>>>(y, h, Hin, nullptr);
    gemm_slow<1><<<gg, 256, 0, stream>>>(h, W_o, nullptr, b_o, nullptr, y, nullptr);
  }
}

// Round 4
// 443.688 us; speedup vs baseline: 2.6726x; 1.1734x over previous
//
#include <hip/hip_runtime.h>
#include <stdint.h>

#define B_ 8
#define L_ 4096
#define D_ 1024
#define M_ (B_*L_)        // 32768 rows
#define CHUNKS 64
#define TCH (L_/CHUNKS)   // 64

typedef float f32x4 __attribute__((ext_vector_type(4)));
typedef float f32x2 __attribute__((ext_vector_type(2)));
typedef short short8 __attribute__((ext_vector_type(8)));
typedef unsigned short ushort4v __attribute__((ext_vector_type(4)));

static __device__ __forceinline__ unsigned short f2bf(float f) {
  union { float f; unsigned u; } v; v.f = f;
  unsigned r = v.u + 0x7FFFu + ((v.u >> 16) & 1u);   // round-to-nearest-even
  return (unsigned short)(r >> 16);
}
static __device__ __forceinline__ float bf2f(unsigned short u) {
  union { unsigned u; float f; } v; v.u = ((unsigned)u) << 16; return v.f;
}

#define GLOAD16(g, l) \
  __builtin_amdgcn_global_load_lds((__attribute__((address_space(1))) const void*)(g), \
                                   (__attribute__((address_space(3))) void*)(l), 16, 0, 0)

// ---------------------------------------------------------------------------
// fp32 -> bf16 convert, 8 elems/thread
// ---------------------------------------------------------------------------
__global__ __launch_bounds__(256)
void cvt_bf16(const float* __restrict__ src, unsigned short* __restrict__ dst, int n8)
{
  int gid = blockIdx.x * 256 + threadIdx.x;
  if (gid >= n8) return;
  const f32x4* s = (const f32x4*)(src + (size_t)gid * 8);
  f32x4 v0 = s[0], v1 = s[1];
  union { short8 v; unsigned short u[8]; } w;
  w.u[0] = f2bf(v0[0]); w.u[1] = f2bf(v0[1]); w.u[2] = f2bf(v0[2]); w.u[3] = f2bf(v0[3]);
  w.u[4] = f2bf(v1[0]); w.u[5] = f2bf(v1[1]); w.u[6] = f2bf(v1[2]); w.u[7] = f2bf(v1[3]);
  *(short8*)(dst + (size_t)gid * 8) = w.v;
}

// ---------------------------------------------------------------------------
// Single-B GEMM, 3-deep ring pipeline with counted vmcnt (T3-min + T4 + T5).
// C[m,e] = sum_d A[m,d]*W[e,d] + bias[e]   (NT; M=32768, N=1024, K=1024)
// 128x128 tile, BK=32, 4 waves (2x2 of 64x64), 16x16x32 bf16 MFMA.
// LDS read-swizzle slot^=(row>>1)&3 realized by pre-swizzled global source
// (gload_lds dest stays linear — rule 21).  OBF=1: bf16 output.
// ---------------------------------------------------------------------------
template<int OBF>
__global__ __launch_bounds__(256, 3)
void gemm_nt(const unsigned short* __restrict__ A,
             const unsigned short* __restrict__ Bw,
             const float* __restrict__ bias,
             float* __restrict__ outf,
             unsigned short* __restrict__ outb)
{
  __shared__ unsigned short As[3][4096];   // 3 x 8KB ring
  __shared__ unsigned short Bs[3][4096];

  const int tid  = threadIdx.x;
  const int lane = tid & 63;
  const int wave = tid >> 6;
  const int wr = wave >> 1, wc = wave & 1;
  const int frow = lane & 15, ks = lane >> 4;
  const int xslot = (ks ^ ((frow >> 1) & 3)) << 4;   // swizzled 16B slot (bytes)

  // XCD-bijective swizzle (nwg % 8 == 0), bn fastest within an XCD chunk
  const int nwg = gridDim.x;
  const int wg  = (blockIdx.x & 7) * (nwg >> 3) + (blockIdx.x >> 3);
  const int bm  = (wg >> 3) * 128;
  const int bn  = (wg & 7) * 128;

  // staging: 128x32 bf16 tile = 8KB/matrix, 2 gload16/thread/matrix
  const int so   = tid * 16;                            // linear LDS dest
  const int srow = tid >> 2;                            // 0..63
  const int g16  = ((tid & 3) ^ ((tid >> 3) & 3)) << 4; // pre-swizzled slot

  const char* pA0 = (const char*)A  + (size_t)(bm + srow) * 2048 + g16;
  const char* pA1 = pA0 + (size_t)64 * 2048;
  const char* pB0 = (const char*)Bw + (size_t)(bn + srow) * 2048 + g16;
  const char* pB1 = pB0 + (size_t)64 * 2048;

  f32x4 acc[4][4] = {};

  auto stage = [&](int t, int bb) {
    int kb = t * 64;
    GLOAD16(pA0 + kb, (char*)As[bb] + so);
    GLOAD16(pA1 + kb, (char*)As[bb] + so + 4096);
    GLOAD16(pB0 + kb, (char*)Bs[bb] + so);
    GLOAD16(pB1 + kb, (char*)Bs[bb] + so + 4096);
  };

  auto compute = [&](int bb) {
    short8 af[4], bf[4];
    #pragma unroll
    for (int i = 0; i < 4; ++i) {
      int ar = wr * 64 + i * 16 + frow;
      af[i] = *(const short8*)((const char*)As[bb] + ar * 64 + xslot);
      int br = wc * 64 + i * 16 + frow;
      bf[i] = *(const short8*)((const char*)Bs[bb] + br * 64 + xslot);
    }
    __builtin_amdgcn_s_setprio(1);
    #pragma unroll
    for (int i = 0; i < 4; ++i)
      #pragma unroll
      for (int j = 0; j < 4; ++j)
        acc[i][j] = __builtin_amdgcn_mfma_f32_16x16x32_bf16(af[i], bf[j], acc[i][j], 0, 0, 0);
    __builtin_amdgcn_s_setprio(0);
  };

  stage(0, 0);
  stage(1, 1);
  int bb = 0;
  for (int t = 0; t < 30; ++t) {
    asm volatile("s_waitcnt vmcnt(4)" ::: "memory");   // stage(t) done; t+1 in flight
    __builtin_amdgcn_s_barrier();
    // prefetch tile t+2 into ring slot (t+2)%3 == (t-1)%3 (safe: reads done)
    int nb = bb + 2; if (nb >= 3) nb -= 3;
    stage(t + 2, nb);
    compute(bb);
    ++bb; if (bb == 3) bb = 0;
  }
  // t = 30: stages 30,31 outstanding
  asm volatile("s_waitcnt vmcnt(4)" ::: "memory");
  __builtin_amdgcn_s_barrier();
  compute(bb);
  ++bb; if (bb == 3) bb = 0;
  // t = 31
  asm volatile("s_waitcnt vmcnt(0)" ::: "memory");
  __builtin_amdgcn_s_barrier();
  compute(bb);

  float bv[4];
  #pragma unroll
  for (int j = 0; j < 4; ++j) bv[j] = bias[bn + wc * 64 + j * 16 + frow];
  #pragma unroll
  for (int i = 0; i < 4; ++i) {
    int row = bm + wr * 64 + i * 16 + ks * 4;
    #pragma unroll
    for (int j = 0; j < 4; ++j) {
      int col = bn + wc * 64 + j * 16 + frow;
      #pragma unroll
      for (int r = 0; r < 4; ++r) {
        float v = acc[i][j][r] + bv[j];
        if constexpr (OBF) outb[(size_t)(row + r) * D_ + col] = f2bf(v);
        else               outf[(size_t)(row + r) * D_ + col] = v;
      }
    }
  }
}

// ---------------------------------------------------------------------------
// Gate transform from bf16 raw z values
// ---------------------------------------------------------------------------
static __device__ __forceinline__ void gate1(float zf, float zi, float lin,
                                             float& f, float& inp)
{
  float rem = lin / (1.0f + __expf(-zf));
  float ez  = __expf(2.0f * zi);
  float th  = 1.0f - 2.0f / (ez + 1.0f);
  f = 1.0f - rem;
  inp = th * rem;
}

// ---------------------------------------------------------------------------
// Chunked parallel scan, bf16 z inputs, 4 channels/thread.
// grid: B_*CHUNKS blocks x 256 threads (1024 channels per (b,c))
// ---------------------------------------------------------------------------
__global__ __launch_bounds__(256)
void scan_partial_b(const unsigned short* __restrict__ zf,
                    const unsigned short* __restrict__ zi,
                    float* __restrict__ Ag, float* __restrict__ Ug)
{
  int blk = blockIdx.x;
  int b = blk >> 6, c = blk & 63;
  int e = threadIdx.x << 2;
  float lin0 = (float)e * (1.0f / 1023.0f);
  size_t base = ((size_t)b * L_ + (size_t)c * TCH) * D_ + e;
  f32x4 a = {1.f,1.f,1.f,1.f}, u = {0.f,0.f,0.f,0.f};
  for (int t = 0; t < TCH; ++t) {
    ushort4v f4 = *(const ushort4v*)(zf + base + (size_t)t * D_);
    ushort4v i4 = *(const ushort4v*)(zi + base + (size_t)t * D_);
    #pragma unroll
    for (int j = 0; j < 4; ++j) {
      float fg, inp;
      gate1(bf2f(f4[j]), bf2f(i4[j]), lin0 + (float)j * (1.0f/1023.0f), fg, inp);
      u[j] = fmaf(fg, u[j], inp);
      a[j] *= fg;
    }
  }
  size_t o = (size_t)(b * CHUNKS + c) * D_ + e;
  *(f32x4*)(Ag + o) = a;
  *(f32x4*)(Ug + o) = u;
}

__global__ __launch_bounds__(256)
void scan_carry(const float* __restrict__ Ag, const float* __restrict__ Ug,
                const float* __restrict__ hidden, float* __restrict__ Hin)
{
  int gid = blockIdx.x * 256 + threadIdx.x;  // B_*D_/4 threads
  int b = gid >> 8;
  int e = (gid & 255) << 2;
  f32x4 h = *(const f32x4*)(hidden + (size_t)b * D_ + e);
  for (int c = 0; c < CHUNKS; ++c) {
    size_t o = (size_t)(b * CHUNKS + c) * D_ + e;
    *(f32x4*)(Hin + o) = h;
    f32x4 A = *(const f32x4*)(Ag + o);
    f32x4 U = *(const f32x4*)(Ug + o);
    h = A * h + U;
  }
}

__global__ __launch_bounds__(256)
void scan_apply_b(const unsigned short* __restrict__ zf,
                  const unsigned short* __restrict__ zi,
                  const float* __restrict__ Hin,
                  float* __restrict__ hout, unsigned short* __restrict__ hb)
{
  int blk = blockIdx.x;
  int b = blk >> 6, c = blk & 63;
  int e = threadIdx.x << 2;
  float lin0 = (float)e * (1.0f / 1023.0f);
  size_t base = ((size_t)b * L_ + (size_t)c * TCH) * D_ + e;
  f32x4 h = *(const f32x4*)(Hin + (size_t)(b * CHUNKS + c) * D_ + e);
  for (int t = 0; t < TCH; ++t) {
    size_t o = base + (size_t)t * D_;
    ushort4v f4 = *(const ushort4v*)(zf + o);
    ushort4v i4 = *(const ushort4v*)(zi + o);
    #pragma unroll
    for (int j = 0; j < 4; ++j) {
      float fg, inp;
      gate1(bf2f(f4[j]), bf2f(i4[j]), lin0 + (float)j * (1.0f/1023.0f), fg, inp);
      h[j] = fmaf(fg, h[j], inp);
    }
    *(f32x4*)(hout + o) = h;
    ushort4v p;
    p[0] = f2bf(h[0]); p[1] = f2bf(h[1]); p[2] = f2bf(h[2]); p[3] = f2bf(h[3]);
    *(ushort4v*)(hb + o) = p;
  }
}

// ---------------------------------------------------------------------------
// Slow fallback (fp32 in, reg-staged convert) — only if ws too small.
// ---------------------------------------------------------------------------
template<int MODE>
__global__ __launch_bounds__(256, 2)
void gemm_slow(const float* __restrict__ A, const float* __restrict__ B0,
               const float* __restrict__ B1, const float* __restrict__ bias0,
               const float* __restrict__ bias1, float* __restrict__ out0,
               float* __restrict__ out1)
{
  constexpr int BK = 32;
  __shared__ unsigned short As[128 * BK];
  __shared__ unsigned short Bs0[128 * BK];
  __shared__ unsigned short Bs1[(MODE == 0) ? (128 * BK) : 8];

  const int tid = threadIdx.x, lane = tid & 63, wave = tid >> 6;
  const int wr = wave >> 1, wc = wave & 1;
  const int bm = blockIdx.x * 128, bn = blockIdx.y * 128;
  f32x4 acc0[4][4] = {};
  f32x4 acc1[(MODE == 0) ? 4 : 1][(MODE == 0) ? 4 : 1] = {};
  const int frow = lane & 15, kslot = lane >> 4;
  const int xs = kslot ^ (frow & 3);

  auto stage = [&](const float* src, unsigned short* dst) {
    #pragma unroll
    for (int p = 0; p < 4; ++p) {
      int g = p * 256 + tid;
      int row = g >> 3, kq = (g & 7) << 2;
      f32x4 v = *(const f32x4*)(src + (size_t)row * D_ + kq);
      ushort4v w;
      w[0] = f2bf(v[0]); w[1] = f2bf(v[1]); w[2] = f2bf(v[2]); w[3] = f2bf(v[3]);
      int byte = kq << 1, slot = byte >> 4, sub = byte & 15;
      int off = row * 64 + ((slot ^ (row & 3)) << 4) + sub;
      *(ushort4v*)((char*)dst + off) = w;
    }
  };

  for (int k0 = 0; k0 < D_; k0 += BK) {
    stage(A + (size_t)bm * D_ + k0, As);
    stage(B0 + (size_t)bn * D_ + k0, Bs0);
    if constexpr (MODE == 0) stage(B1 + (size_t)bn * D_ + k0, Bs1);
    __syncthreads();
    short8 af[4], bf0[4], bf1[4];
    #pragma unroll
    for (int i = 0; i < 4; ++i) {
      int ar = wr * 64 + i * 16 + frow;
      af[i] = *(const short8*)((const char*)As + ar * 64 + (xs << 4));
      int br = wc * 64 + i * 16 + frow;
      bf0[i] = *(const short8*)((const char*)Bs0 + br * 64 + (xs << 4));
      if constexpr (MODE == 0)
        bf1[i] = *(const short8*)((const char*)Bs1 + br * 64 + (xs << 4));
    }
    #pragma unroll
    for (int i = 0; i < 4; ++i)
      #pragma unroll
      for (int j = 0; j < 4; ++j) {
        acc0[i][j] = __builtin_amdgcn_mfma_f32_16x16x32_bf16(af[i], bf0[j], acc0[i][j], 0, 0, 0);
        if constexpr (MODE == 0)
          acc1[i][j] = __builtin_amdgcn_mfma_f32_16x16x32_bf16(af[i], bf1[j], acc1[i][j], 0, 0, 0);
      }
    __syncthreads();
  }
  #pragma unroll
  for (int i = 0; i < 4; ++i)
    #pragma unroll
    for (int j = 0; j < 4; ++j)
      #pragma unroll
      for (int r = 0; r < 4; ++r) {
        int row = bm + wr * 64 + i * 16 + (lane >> 4) * 4 + r;
        int col = bn + wc * 64 + j * 16 + (lane & 15);
        size_t idx = (size_t)row * D_ + col;
        if constexpr (MODE == 0) {
          float zf = acc0[i][j][r] + bias0[col];
          float linv = (float)col * (1.0f / 1023.0f);
          float rem = linv / (1.0f + __expf(-zf));
          float zi = acc1[i][j][r] + bias1[col];
          float e2 = __expf(2.0f * zi);
          float th = 1.0f - 2.0f / (e2 + 1.0f);
          out0[idx] = 1.0f - rem;
          out1[idx] = th * rem;
        } else {
          out0[idx] = acc0[i][j][r] + bias0[col];
        }
      }
}

template<int GATED>
__global__ __launch_bounds__(256)
void scan_partial_f(const float* __restrict__ p0, const float* __restrict__ p1,
                    float* __restrict__ Ag, float* __restrict__ Ug)
{
  int blk = blockIdx.x;                      // B_*CHUNKS*2 blocks
  int b = blk >> 7;
  int c = (blk >> 1) & (CHUNKS - 1);
  int e = ((blk & 1) << 9) + threadIdx.x * 2;
  size_t base = ((size_t)b * L_ + (size_t)c * TCH) * D_ + e;
  f32x2 a = {1.0f, 1.0f}, u = {0.0f, 0.0f};
  for (int t = 0; t < TCH; ++t) {
    f32x2 f = *(const f32x2*)(p0 + base + (size_t)t * D_);
    f32x2 i = *(const f32x2*)(p1 + base + (size_t)t * D_);
    u = f * u + i;
    a = a * f;
  }
  size_t o = (size_t)(b * CHUNKS + c) * D_ + e;
  *(f32x2*)(Ag + o) = a;
  *(f32x2*)(Ug + o) = u;
}

__global__ __launch_bounds__(256)
void scan_apply_f(const float* __restrict__ p0, float* __restrict__ p1_io,
                  const float* __restrict__ Hin)
{
  int blk = blockIdx.x;
  int b = blk >> 7;
  int c = (blk >> 1) & (CHUNKS - 1);
  int e = ((blk & 1) << 9) + threadIdx.x * 2;
  size_t base = ((size_t)b * L_ + (size_t)c * TCH) * D_ + e;
  f32x2 h = *(const f32x2*)(Hin + (size_t)(b * CHUNKS + c) * D_ + e);
  for (int t = 0; t < TCH; ++t) {
    size_t o = base + (size_t)t * D_;
    f32x2 f = *(const f32x2*)(p0 + o);
    f32x2 i = *(const f32x2*)(p1_io + o);
    h = f * h + i;
    *(f32x2*)(p1_io + o) = h;
  }
}

// ---------------------------------------------------------------------------
extern "C" void kernel_launch(void* const* d_in, const int* in_sizes, int n_in,
                              void* d_out, int out_size, void* d_ws, size_t ws_size,
                              hipStream_t stream)
{
  const float* x      = (const float*)d_in[0];
  const float* hidden = (const float*)d_in[1];
  const float* W_f    = (const float*)d_in[2];
  const float* b_f    = (const float*)d_in[3];
  const float* W_i    = (const float*)d_in[4];
  const float* b_i    = (const float*)d_in[5];
  const float* W_o    = (const float*)d_in[6];
  const float* b_o    = (const float*)d_in[7];

  float* y = (float*)d_out;
  float* h = y + (size_t)M_ * D_;

  const size_t xb_elems = (size_t)M_ * D_;
  const size_t w_elems  = (size_t)D_ * D_;
  const size_t agg      = (size_t)B_ * CHUNKS * D_;
  const size_t need = (xb_elems * 3 + 3 * w_elems) * 2 + agg * 3 * 4;

  if (ws_size >= need) {
    unsigned short* xb  = (unsigned short*)d_ws;       // bf16 x, later bf16 h
    unsigned short* wfb = xb + xb_elems;
    unsigned short* wib = wfb + w_elems;
    unsigned short* wob = wib + w_elems;
    unsigned short* zfb = wob + w_elems;               // bf16 zf
    unsigned short* zib = zfb + xb_elems;              // bf16 zi
    float* Ag  = (float*)(zib + xb_elems);
    float* Ug  = Ag + agg;
    float* Hin = Ug + agg;

    cvt_bf16<<<(int)(xb_elems / 8 / 256), 256, 0, stream>>>(x,   xb,  (int)(xb_elems / 8));
    cvt_bf16<<<(int)(w_elems / 8 / 256), 256, 0, stream>>>(W_f, wfb, (int)(w_elems / 8));
    cvt_bf16<<<(int)(w_elems / 8 / 256), 256, 0, stream>>>(W_i, wib, (int)(w_elems / 8));
    cvt_bf16<<<(int)(w_elems / 8 / 256), 256, 0, stream>>>(W_o, wob, (int)(w_elems / 8));

    int gblocks = (M_ / 128) * (D_ / 128);   // 2048
    gemm_nt<1><<<gblocks, 256, 0, stream>>>(xb, wfb, b_f, nullptr, zfb);
    gemm_nt<1><<<gblocks, 256, 0, stream>>>(xb, wib, b_i, nullptr, zib);

    int pblocks = B_ * CHUNKS;               // 512
    scan_partial_b<<<pblocks, 256, 0, stream>>>(zfb, zib, Ag, Ug);
    scan_carry<<<(B_ * D_ / 4) / 256, 256, 0, stream>>>(Ag, Ug, hidden, Hin);
    scan_apply_b<<<pblocks, 256, 0, stream>>>(zfb, zib, Hin, h, xb); // h fp32 + bf16

    gemm_nt<0><<<gblocks, 256, 0, stream>>>(xb, wob, b_o, y, nullptr);
  } else {
    float* Ag  = (float*)d_ws;
    float* Ug  = Ag + agg;
    float* Hin = Ug + agg;
    dim3 gg(M_ / 128, D_ / 128);
    int pblocks = B_ * CHUNKS * 2;

    gemm_slow<0><<<gg, 256, 0, stream>>>(x, W_f, W_i, b_f, b_i, y, h);
    scan_partial_f<0><<<pblocks, 256, 0, stream>>>(y, h, Ag, Ug);
    scan_carry<<<(B_ * D_ / 4) / 256, 256, 0, stream>>>(Ag, Ug, hidden, Hin);
    scan_apply_f<<<pblocks, 256, 0, stream>>>(y, h, Hin);
    gemm_slow<1><<<gg, 256, 0, stream>>>(h, W_o, nullptr, b_o, nullptr, y, nullptr);
  }
}

// Round 5
// 423.747 us; speedup vs baseline: 2.7984x; 1.0471x over previous
//
#include <hip/hip_runtime.h>
#include <stdint.h>

#define B_ 8
#define L_ 4096
#define D_ 1024
#define M_ (B_*L_)        // 32768 rows
#define CHUNKS 64
#define TCH (L_/CHUNKS)   // 64

typedef float f32x4 __attribute__((ext_vector_type(4)));
typedef float f32x2 __attribute__((ext_vector_type(2)));
typedef short short8 __attribute__((ext_vector_type(8)));
typedef unsigned short ushort4v __attribute__((ext_vector_type(4)));

static __device__ __forceinline__ unsigned short f2bf(float f) {
  union { float f; unsigned u; } v; v.f = f;
  unsigned r = v.u + 0x7FFFu + ((v.u >> 16) & 1u);   // round-to-nearest-even
  return (unsigned short)(r >> 16);
}
static __device__ __forceinline__ float bf2f(unsigned short u) {
  union { unsigned u; float f; } v; v.u = ((unsigned)u) << 16; return v.f;
}

#define GLOAD16(g, l) \
  __builtin_amdgcn_global_load_lds((__attribute__((address_space(1))) const void*)(g), \
                                   (__attribute__((address_space(3))) void*)(l), 16, 0, 0)

// ---------------------------------------------------------------------------
// fp32 -> bf16 convert, 8 elems/thread
// ---------------------------------------------------------------------------
__global__ __launch_bounds__(256)
void cvt_bf16(const float* __restrict__ src, unsigned short* __restrict__ dst, int n8)
{
  int gid = blockIdx.x * 256 + threadIdx.x;
  if (gid >= n8) return;
  const f32x4* s = (const f32x4*)(src + (size_t)gid * 8);
  f32x4 v0 = s[0], v1 = s[1];
  union { short8 v; unsigned short u[8]; } w;
  w.u[0] = f2bf(v0[0]); w.u[1] = f2bf(v0[1]); w.u[2] = f2bf(v0[2]); w.u[3] = f2bf(v0[3]);
  w.u[4] = f2bf(v1[0]); w.u[5] = f2bf(v1[1]); w.u[6] = f2bf(v1[2]); w.u[7] = f2bf(v1[3]);
  *(short8*)(dst + (size_t)gid * 8) = w.v;
}

// ---------------------------------------------------------------------------
// 256x256 8-wave GEMM, 4-phase/K-tile schedule, counted vmcnt (T2+T3+T4+T5).
// C[m,e] = sum_d A[m,d]*W[e,d] + bias[e]   (NT; M=32768, N=1024, K=1024)
// BK=64 split in two 32-col K-slice chunks; LDS chunk = [256 rows][32 cols]
// bf16 (16KB, 64B rows = 4 x 16B slots). Swizzle: physical slot =
// logical slot ^ ((row>>1)&3)  (involution; applied at pre-swizzled global
// source for gload_lds + swizzled ds_read — rule 21).
// Chunk stream C_n (n=4T+q; q:0=Akk0,1=Bkk0,2=Akk1,3=Bkk1). Issue C_{4t+p+6}
// at phase p of tile t; vmcnt(8) at odd phases; tail peeled (8,4 / 0,-).
// ---------------------------------------------------------------------------
template<int OBF>
__global__ __launch_bounds__(512, 2)
void gemm256(const unsigned short* __restrict__ A,
             const unsigned short* __restrict__ Bw,
             const float* __restrict__ bias,
             float* __restrict__ outf,
             unsigned short* __restrict__ outb)
{
  __shared__ unsigned short lds[65536];   // 128KB: A [2buf][2kk][16KB] | B same at +64KB
  char* ldsb = (char*)lds;

  const int tid  = threadIdx.x;
  const int lane = tid & 63;
  const int wid  = tid >> 6;          // 0..7
  const int wm   = wid >> 2;          // 0..1  (row half)
  const int wn   = wid & 3;           // 0..3  (col quarter)
  const int frow = lane & 15, ks = lane >> 4;
  const int xsw  = (ks ^ ((frow >> 1) & 3)) << 4;    // swizzled 16B slot (bytes)

  // XCD-bijective swizzle; per-XCD chunk shares one bn (B panel L2-resident)
  const int nwg = gridDim.x;                  // 512
  const int wg  = (blockIdx.x & 7) * (nwg >> 3) + (blockIdx.x >> 3);
  const int bm  = (wg & 127) * 256;
  const int bn  = (wg >> 7) * 256;

  // staging source: thread stages physical slots (r0, sc0) and (r0+128, sc0)
  const int r0  = tid >> 2;
  const int scl = ((tid & 3) ^ ((r0 >> 1) & 3)) << 4;   // pre-swizzled k-slot (bytes)
  const char* pA = (const char*)A  + (size_t)(bm + r0) * 2048 + scl;
  const char* pB = (const char*)Bw + (size_t)(bn + r0) * 2048 + scl;
  const int dst16 = tid * 16;

  f32x4 acc[8][4] = {};
  short8 aq[4], bq[4];

  auto stgA = [&](int T, int kk, int buf) {
    const char* s = pA + T * 128 + kk * 64;
    char* d = ldsb + buf * 32768 + kk * 16384 + dst16;
    GLOAD16(s, d);
    GLOAD16(s + (size_t)128 * 2048, d + 8192);
  };
  auto stgB = [&](int T, int kk, int buf) {
    const char* s = pB + T * 128 + kk * 64;
    char* d = ldsb + 65536 + buf * 32768 + kk * 16384 + dst16;
    GLOAD16(s, d);
    GLOAD16(s + (size_t)128 * 2048, d + 8192);
  };
  auto ldA4 = [&](const char* LA, int kk, int ih) {
    const char* base = LA + kk * 16384 + (wm * 128 + ih * 64 + frow) * 64 + xsw;
    aq[0] = *(const short8*)(base);
    aq[1] = *(const short8*)(base + 1024);
    aq[2] = *(const short8*)(base + 2048);
    aq[3] = *(const short8*)(base + 3072);
  };
  auto ldB4 = [&](const char* LB, int kk) {
    const char* base = LB + kk * 16384 + (wn * 64 + frow) * 64 + xsw;
    bq[0] = *(const short8*)(base);
    bq[1] = *(const short8*)(base + 1024);
    bq[2] = *(const short8*)(base + 2048);
    bq[3] = *(const short8*)(base + 3072);
  };
  auto mfma16 = [&](int ih) {
    __builtin_amdgcn_s_setprio(1);
    #pragma unroll
    for (int i2 = 0; i2 < 4; ++i2) {
      #pragma unroll
      for (int j = 0; j < 4; ++j)
        acc[ih * 4 + i2][j] =
          __builtin_amdgcn_mfma_f32_16x16x32_bf16(aq[i2], bq[j], acc[ih * 4 + i2][j], 0, 0, 0);
    }
    __builtin_amdgcn_s_setprio(0);
  };

  // prologue: chunks C0..C5; wait -> C0,C1 resident; 8 loads in flight
  stgA(0, 0, 0); stgB(0, 0, 0);
  stgA(0, 1, 0); stgB(0, 1, 0);
  stgA(1, 0, 1); stgB(1, 0, 1);
  asm volatile("s_waitcnt vmcnt(8)" ::: "memory");
  __builtin_amdgcn_s_barrier();

  for (int t = 0; t < 16; ++t) {
    const int buf = t & 1;
    const char* LA = ldsb + buf * 32768;
    const char* LB = ldsb + 65536 + buf * 32768;
    // ---- phase 0: kk0, i0-3 (reads C_{4t}, C_{4t+1})
    ldB4(LB, 0);
    ldA4(LA, 0, 0);
    if (t < 15) stgA(t + 1, 1, (t + 1) & 1);             // C_{4t+6}
    __builtin_amdgcn_s_barrier();
    asm volatile("s_waitcnt lgkmcnt(0)" ::: "memory");
    mfma16(0);
    __builtin_amdgcn_s_barrier();
    // ---- phase 1: kk0, i4-7 (B held in regs)
    ldA4(LA, 0, 1);
    if (t < 15) stgB(t + 1, 1, (t + 1) & 1);             // C_{4t+7}
    if (t < 15) asm volatile("s_waitcnt vmcnt(8)" ::: "memory");  // kk1 chunks ready
    else        asm volatile("s_waitcnt vmcnt(0)" ::: "memory");
    __builtin_amdgcn_s_barrier();
    asm volatile("s_waitcnt lgkmcnt(0)" ::: "memory");
    mfma16(1);
    __builtin_amdgcn_s_barrier();
    // ---- phase 2: kk1, i0-3 (reads C_{4t+2}, C_{4t+3})
    ldB4(LB, 1);
    ldA4(LA, 1, 0);
    if (t < 14) stgA(t + 2, 0, buf);                     // C_{4t+8} (this buf's dead kk0)
    __builtin_amdgcn_s_barrier();
    asm volatile("s_waitcnt lgkmcnt(0)" ::: "memory");
    mfma16(0 + 4 - 4);  // ih=0 quadrant again? no -- see below
    __builtin_amdgcn_s_barrier();
    // ---- phase 3: kk1, i4-7
    ldA4(LA, 1, 1);
    if (t < 14) stgB(t + 2, 0, buf);                     // C_{4t+9}
    if (t < 14) asm volatile("s_waitcnt vmcnt(8)" ::: "memory");  // next tile kk0 ready
    else        asm volatile("s_waitcnt vmcnt(4)" ::: "memory");
    __builtin_amdgcn_s_barrier();
    asm volatile("s_waitcnt lgkmcnt(0)" ::: "memory");
    mfma16(1);
    __builtin_amdgcn_s_barrier();
  }

  float bv[4];
  #pragma unroll
  for (int j = 0; j < 4; ++j) bv[j] = bias[bn + wn * 64 + j * 16 + frow];
  #pragma unroll
  for (int ii = 0; ii < 8; ++ii) {
    int row = bm + wm * 128 + ii * 16 + ks * 4;
    #pragma unroll
    for (int j = 0; j < 4; ++j) {
      int col = bn + wn * 64 + j * 16 + frow;
      #pragma unroll
      for (int r = 0; r < 4; ++r) {
        float v = acc[ii][j][r] + bv[j];
        if constexpr (OBF) outb[(size_t)(row + r) * D_ + col] = f2bf(v);
        else               outf[(size_t)(row + r) * D_ + col] = v;
      }
    }
  }
}

// ---------------------------------------------------------------------------
// Gate transform from raw z values
// ---------------------------------------------------------------------------
static __device__ __forceinline__ void gate1(float zf, float zi, float lin,
                                             float& f, float& inp)
{
  float rem = lin / (1.0f + __expf(-zf));
  float ez  = __expf(2.0f * zi);
  float th  = 1.0f - 2.0f / (ez + 1.0f);
  f = 1.0f - rem;
  inp = th * rem;
}

// ---------------------------------------------------------------------------
// Chunked parallel scan, bf16 z inputs, 4 channels/thread.
// ---------------------------------------------------------------------------
__global__ __launch_bounds__(256)
void scan_partial_b(const unsigned short* __restrict__ zf,
                    const unsigned short* __restrict__ zi,
                    float* __restrict__ Ag, float* __restrict__ Ug)
{
  int blk = blockIdx.x;
  int b = blk >> 6, c = blk & 63;
  int e = threadIdx.x << 2;
  float lin0 = (float)e * (1.0f / 1023.0f);
  size_t base = ((size_t)b * L_ + (size_t)c * TCH) * D_ + e;
  f32x4 a = {1.f,1.f,1.f,1.f}, u = {0.f,0.f,0.f,0.f};
  for (int t = 0; t < TCH; ++t) {
    ushort4v f4 = *(const ushort4v*)(zf + base + (size_t)t * D_);
    ushort4v i4 = *(const ushort4v*)(zi + base + (size_t)t * D_);
    #pragma unroll
    for (int j = 0; j < 4; ++j) {
      float fg, inp;
      gate1(bf2f(f4[j]), bf2f(i4[j]), lin0 + (float)j * (1.0f/1023.0f), fg, inp);
      u[j] = fmaf(fg, u[j], inp);
      a[j] *= fg;
    }
  }
  size_t o = (size_t)(b * CHUNKS + c) * D_ + e;
  *(f32x4*)(Ag + o) = a;
  *(f32x4*)(Ug + o) = u;
}

__global__ __launch_bounds__(256)
void scan_carry(const float* __restrict__ Ag, const float* __restrict__ Ug,
                const float* __restrict__ hidden, float* __restrict__ Hin)
{
  int gid = blockIdx.x * 256 + threadIdx.x;  // B_*D_/4 threads
  int b = gid >> 8;
  int e = (gid & 255) << 2;
  f32x4 h = *(const f32x4*)(hidden + (size_t)b * D_ + e);
  for (int c = 0; c < CHUNKS; ++c) {
    size_t o = (size_t)(b * CHUNKS + c) * D_ + e;
    *(f32x4*)(Hin + o) = h;
    f32x4 A = *(const f32x4*)(Ag + o);
    f32x4 U = *(const f32x4*)(Ug + o);
    h = A * h + U;
  }
}

__global__ __launch_bounds__(256)
void scan_apply_b(const unsigned short* __restrict__ zf,
                  const unsigned short* __restrict__ zi,
                  const float* __restrict__ Hin,
                  float* __restrict__ hout, unsigned short* __restrict__ hb)
{
  int blk = blockIdx.x;
  int b = blk >> 6, c = blk & 63;
  int e = threadIdx.x << 2;
  float lin0 = (float)e * (1.0f / 1023.0f);
  size_t base = ((size_t)b * L_ + (size_t)c * TCH) * D_ + e;
  f32x4 h = *(const f32x4*)(Hin + (size_t)(b * CHUNKS + c) * D_ + e);
  for (int t = 0; t < TCH; ++t) {
    size_t o = base + (size_t)t * D_;
    ushort4v f4 = *(const ushort4v*)(zf + o);
    ushort4v i4 = *(const ushort4v*)(zi + o);
    #pragma unroll
    for (int j = 0; j < 4; ++j) {
      float fg, inp;
      gate1(bf2f(f4[j]), bf2f(i4[j]), lin0 + (float)j * (1.0f/1023.0f), fg, inp);
      h[j] = fmaf(fg, h[j], inp);
    }
    *(f32x4*)(hout + o) = h;
    ushort4v p;
    p[0] = f2bf(h[0]); p[1] = f2bf(h[1]); p[2] = f2bf(h[2]); p[3] = f2bf(h[3]);
    *(ushort4v*)(hb + o) = p;
  }
}

// ---------------------------------------------------------------------------
// Slow fallback (fp32 in) — only if ws too small (never expected).
// ---------------------------------------------------------------------------
template<int MODE>
__global__ __launch_bounds__(256, 2)
void gemm_slow(const float* __restrict__ A, const float* __restrict__ B0,
               const float* __restrict__ B1, const float* __restrict__ bias0,
               const float* __restrict__ bias1, float* __restrict__ out0,
               float* __restrict__ out1)
{
  constexpr int BK = 32;
  __shared__ unsigned short As[128 * BK];
  __shared__ unsigned short Bs0[128 * BK];
  __shared__ unsigned short Bs1[(MODE == 0) ? (128 * BK) : 8];

  const int tid = threadIdx.x, lane = tid & 63, wave = tid >> 6;
  const int wr = wave >> 1, wc = wave & 1;
  const int bm = blockIdx.x * 128, bn = blockIdx.y * 128;
  f32x4 acc0[4][4] = {};
  f32x4 acc1[(MODE == 0) ? 4 : 1][(MODE == 0) ? 4 : 1] = {};
  const int frow = lane & 15, kslot = lane >> 4;
  const int xs = kslot ^ (frow & 3);

  auto stage = [&](const float* src, unsigned short* dst) {
    #pragma unroll
    for (int p = 0; p < 4; ++p) {
      int g = p * 256 + tid;
      int row = g >> 3, kq = (g & 7) << 2;
      f32x4 v = *(const f32x4*)(src + (size_t)row * D_ + kq);
      ushort4v w;
      w[0] = f2bf(v[0]); w[1] = f2bf(v[1]); w[2] = f2bf(v[2]); w[3] = f2bf(v[3]);
      int byte = kq << 1, slot = byte >> 4, sub = byte & 15;
      int off = row * 64 + ((slot ^ (row & 3)) << 4) + sub;
      *(ushort4v*)((char*)dst + off) = w;
    }
  };

  for (int k0 = 0; k0 < D_; k0 += BK) {
    stage(A + (size_t)bm * D_ + k0, As);
    stage(B0 + (size_t)bn * D_ + k0, Bs0);
    if constexpr (MODE == 0) stage(B1 + (size_t)bn * D_ + k0, Bs1);
    __syncthreads();
    short8 af[4], bf0[4], bf1[4];
    #pragma unroll
    for (int i = 0; i < 4; ++i) {
      int ar = wr * 64 + i * 16 + frow;
      af[i] = *(const short8*)((const char*)As + ar * 64 + (xs << 4));
      int br = wc * 64 + i * 16 + frow;
      bf0[i] = *(const short8*)((const char*)Bs0 + br * 64 + (xs << 4));
      if constexpr (MODE == 0)
        bf1[i] = *(const short8*)((const char*)Bs1 + br * 64 + (xs << 4));
    }
    #pragma unroll
    for (int i = 0; i < 4; ++i)
      #pragma unroll
      for (int j = 0; j < 4; ++j) {
        acc0[i][j] = __builtin_amdgcn_mfma_f32_16x16x32_bf16(af[i], bf0[j], acc0[i][j], 0, 0, 0);
        if constexpr (MODE == 0)
          acc1[i][j] = __builtin_amdgcn_mfma_f32_16x16x32_bf16(af[i], bf1[j], acc1[i][j], 0, 0, 0);
      }
    __syncthreads();
  }
  #pragma unroll
  for (int i = 0; i < 4; ++i)
    #pragma unroll
    for (int j = 0; j < 4; ++j)
      #pragma unroll
      for (int r = 0; r < 4; ++r) {
        int row = bm + wr * 64 + i * 16 + (lane >> 4) * 4 + r;
        int col = bn + wc * 64 + j * 16 + (lane & 15);
        size_t idx = (size_t)row * D_ + col;
        if constexpr (MODE == 0) {
          float zf = acc0[i][j][r] + bias0[col];
          float linv = (float)col * (1.0f / 1023.0f);
          float rem = linv / (1.0f + __expf(-zf));
          float zi = acc1[i][j][r] + bias1[col];
          float e2 = __expf(2.0f * zi);
          float th = 1.0f - 2.0f / (e2 + 1.0f);
          out0[idx] = 1.0f - rem;
          out1[idx] = th * rem;
        } else {
          out0[idx] = acc0[i][j][r] + bias0[col];
        }
      }
}

__global__ __launch_bounds__(256)
void scan_partial_f(const float* __restrict__ p0, const float* __restrict__ p1,
                    float* __restrict__ Ag, float* __restrict__ Ug)
{
  int blk = blockIdx.x;
  int b = blk >> 7;
  int c = (blk >> 1) & (CHUNKS - 1);
  int e = ((blk & 1) << 9) + threadIdx.x * 2;
  size_t base = ((size_t)b * L_ + (size_t)c * TCH) * D_ + e;
  f32x2 a = {1.0f, 1.0f}, u = {0.0f, 0.0f};
  for (int t = 0; t < TCH; ++t) {
    f32x2 f = *(const f32x2*)(p0 + base + (size_t)t * D_);
    f32x2 i = *(const f32x2*)(p1 + base + (size_t)t * D_);
    u = f * u + i;
    a = a * f;
  }
  size_t o = (size_t)(b * CHUNKS + c) * D_ + e;
  *(f32x2*)(Ag + o) = a;
  *(f32x2*)(Ug + o) = u;
}

__global__ __launch_bounds__(256)
void scan_apply_f(const float* __restrict__ p0, float* __restrict__ p1_io,
                  const float* __restrict__ Hin)
{
  int blk = blockIdx.x;
  int b = blk >> 7;
  int c = (blk >> 1) & (CHUNKS - 1);
  int e = ((blk & 1) << 9) + threadIdx.x * 2;
  size_t base = ((size_t)b * L_ + (size_t)c * TCH) * D_ + e;
  f32x2 h = *(const f32x2*)(Hin + (size_t)(b * CHUNKS + c) * D_ + e);
  for (int t = 0; t < TCH; ++t) {
    size_t o = base + (size_t)t * D_;
    f32x2 f = *(const f32x2*)(p0 + o);
    f32x2 i = *(const f32x2*)(p1_io + o);
    h = f * h + i;
    *(f32x2*)(p1_io + o) = h;
  }
}

// ---------------------------------------------------------------------------
extern "C" void kernel_launch(void* const* d_in, const int* in_sizes, int n_in,
                              void* d_out, int out_size, void* d_ws, size_t ws_size,
                              hipStream_t stream)
{
  const float* x      = (const float*)d_in[0];
  const float* hidden = (const float*)d_in[1];
  const float* W_f    = (const float*)d_in[2];
  const float* b_f    = (const float*)d_in[3];
  const float* W_i    = (const float*)d_in[4];
  const float* b_i    = (const float*)d_in[5];
  const float* W_o    = (const float*)d_in[6];
  const float* b_o    = (const float*)d_in[7];

  float* y = (float*)d_out;
  float* h = y + (size_t)M_ * D_;

  const size_t xb_elems = (size_t)M_ * D_;
  const size_t w_elems  = (size_t)D_ * D_;
  const size_t agg      = (size_t)B_ * CHUNKS * D_;
  const size_t need = (xb_elems * 3 + 3 * w_elems) * 2 + agg * 3 * 4;

  if (ws_size >= need) {
    unsigned short* xb  = (unsigned short*)d_ws;       // bf16 x, later bf16 h
    unsigned short* wfb = xb + xb_elems;
    unsigned short* wib = wfb + w_elems;
    unsigned short* wob = wib + w_elems;
    unsigned short* zfb = wob + w_elems;               // bf16 zf
    unsigned short* zib = zfb + xb_elems;              // bf16 zi
    float* Ag  = (float*)(zib + xb_elems);
    float* Ug  = Ag + agg;
    float* Hin = Ug + agg;

    cvt_bf16<<<(int)(xb_elems / 8 / 256), 256, 0, stream>>>(x,   xb,  (int)(xb_elems / 8));
    cvt_bf16<<<(int)(w_elems / 8 / 256), 256, 0, stream>>>(W_f, wfb, (int)(w_elems / 8));
    cvt_bf16<<<(int)(w_elems / 8 / 256), 256, 0, stream>>>(W_i, wib, (int)(w_elems / 8));
    cvt_bf16<<<(int)(w_elems / 8 / 256), 256, 0, stream>>>(W_o, wob, (int)(w_elems / 8));

    int gblocks = (M_ / 256) * (D_ / 256);   // 512
    gemm256<1><<<gblocks, 512, 0, stream>>>(xb, wfb, b_f, nullptr, zfb);
    gemm256<1><<<gblocks, 512, 0, stream>>>(xb, wib, b_i, nullptr, zib);

    int pblocks = B_ * CHUNKS;               // 512
    scan_partial_b<<<pblocks, 256, 0, stream>>>(zfb, zib, Ag, Ug);
    scan_carry<<<(B_ * D_ / 4) / 256, 256, 0, stream>>>(Ag, Ug, hidden, Hin);
    scan_apply_b<<<pblocks, 256, 0, stream>>>(zfb, zib, Hin, h, xb); // h fp32 + bf16

    gemm256<0><<<gblocks, 512, 0, stream>>>(xb, wob, b_o, y, nullptr);
  } else {
    float* Ag  = (float*)d_ws;
    float* Ug  = Ag + agg;
    float* Hin = Ug + agg;
    dim3 gg(M_ / 128, D_ / 128);
    int pblocks = B_ * CHUNKS * 2;

    gemm_slow<0><<<gg, 256, 0, stream>>>(x, W_f, W_i, b_f, b_i, y, h);
    scan_partial_f<<<pblocks, 256, 0, stream>>>(y, h, Ag, Ug);
    scan_carry<<<(B_ * D_ / 4) / 256, 256, 0, stream>>>(Ag, Ug, hidden, Hin);
    scan_apply_f<<<pblocks, 256, 0, stream>>>(y, h, Hin);
    gemm_slow<1><<<gg, 256, 0, stream>>>(h, W_o, nullptr, b_o, nullptr, y, nullptr);
  }
}

// Round 6
// 390.938 us; speedup vs baseline: 3.0332x; 1.0839x over previous
//
#include <hip/hip_runtime.h>
#include <stdint.h>

#define B_ 8
#define L_ 4096
#define D_ 1024
#define M_ (B_*L_)        // 32768 rows
#define CHUNKS 128
#define TCH (L_/CHUNKS)   // 32

typedef float f32x4 __attribute__((ext_vector_type(4)));
typedef float f32x2 __attribute__((ext_vector_type(2)));
typedef short short8 __attribute__((ext_vector_type(8)));
typedef unsigned short ushort4v __attribute__((ext_vector_type(4)));

static __device__ __forceinline__ unsigned short f2bf(float f) {
  union { float f; unsigned u; } v; v.f = f;
  unsigned r = v.u + 0x7FFFu + ((v.u >> 16) & 1u);   // round-to-nearest-even
  return (unsigned short)(r >> 16);
}
static __device__ __forceinline__ float bf2f(unsigned short u) {
  union { unsigned u; float f; } v; v.u = ((unsigned)u) << 16; return v.f;
}

#define GLOAD16(g, l) \
  __builtin_amdgcn_global_load_lds((__attribute__((address_space(1))) const void*)(g), \
                                   (__attribute__((address_space(3))) void*)(l), 16, 0, 0)

// ---------------------------------------------------------------------------
// fp32 -> bf16 converts
// ---------------------------------------------------------------------------
__global__ __launch_bounds__(256)
void cvt_bf16(const float* __restrict__ src, unsigned short* __restrict__ dst, int n8)
{
  int gid = blockIdx.x * 256 + threadIdx.x;
  if (gid >= n8) return;
  const f32x4* s = (const f32x4*)(src + (size_t)gid * 8);
  f32x4 v0 = s[0], v1 = s[1];
  union { short8 v; unsigned short u[8]; } w;
  w.u[0] = f2bf(v0[0]); w.u[1] = f2bf(v0[1]); w.u[2] = f2bf(v0[2]); w.u[3] = f2bf(v0[3]);
  w.u[4] = f2bf(v1[0]); w.u[5] = f2bf(v1[1]); w.u[6] = f2bf(v1[2]); w.u[7] = f2bf(v1[3]);
  *(short8*)(dst + (size_t)gid * 8) = w.v;
}

// 3 weight matrices (D_*D_ each) in one launch: grid = 3 * (D_*D_/8/256)
__global__ __launch_bounds__(256)
void cvt_w3(const float* __restrict__ w0, const float* __restrict__ w1,
            const float* __restrict__ w2, unsigned short* __restrict__ dst)
{
  const int per = (D_ * D_) / 8 / 256;             // blocks per matrix
  int m = blockIdx.x / per;
  int gid = (blockIdx.x % per) * 256 + threadIdx.x;
  const float* src = (m == 0) ? w0 : (m == 1) ? w1 : w2;
  const f32x4* s = (const f32x4*)(src + (size_t)gid * 8);
  f32x4 v0 = s[0], v1 = s[1];
  union { short8 v; unsigned short u[8]; } w;
  w.u[0] = f2bf(v0[0]); w.u[1] = f2bf(v0[1]); w.u[2] = f2bf(v0[2]); w.u[3] = f2bf(v0[3]);
  w.u[4] = f2bf(v1[0]); w.u[5] = f2bf(v1[1]); w.u[6] = f2bf(v1[2]); w.u[7] = f2bf(v1[3]);
  *(short8*)(dst + (size_t)m * D_ * D_ + (size_t)gid * 8) = w.v;
}

// ---------------------------------------------------------------------------
// 256x256 8-wave GEMM, 4-phase/K-tile, counted vmcnt (T2+T3+T4+T5).
// MODE 0: stacked gates — Bw is [2048][1024] ([W_f;W_i]); planes zf/zi bf16.
// MODE 1: y = h·W_o^T + b_o — Bw [1024][1024], fp32 out.
// A-locality dispatch: the 32 co-resident blocks of an XCD (1 block/CU,
// xcd = idx&7) cover {GBM bm-panels} x {ALL bn tiles}, so each A panel is
// fetched once into that XCD's L2 and shared by all its bn readers.
// ---------------------------------------------------------------------------
template<int MODE>
__global__ __launch_bounds__(512, 2)
void gemm256(const unsigned short* __restrict__ A,
             const unsigned short* __restrict__ Bw,
             const float* __restrict__ bias0,
             const float* __restrict__ bias1,
             unsigned short* __restrict__ ob0,   // zf (MODE 0)
             unsigned short* __restrict__ ob1,   // zi (MODE 0)
             float* __restrict__ of)             // y  (MODE 1)
{
  __shared__ unsigned short lds[65536];   // 128KB: A [2buf][2kk][16KB] | B at +64KB
  char* ldsb = (char*)lds;

  const int tid  = threadIdx.x;
  const int lane = tid & 63;
  const int wid  = tid >> 6;          // 0..7
  const int wm   = wid >> 2;          // 0..1  (row half)
  const int wn   = wid & 3;           // 0..3  (col quarter)
  const int frow = lane & 15, ks = lane >> 4;
  const int xsw  = (ks ^ ((frow >> 1) & 3)) << 4;    // swizzled 16B slot (bytes)

  // A-locality dispatch mapping
  constexpr int NBN = (MODE == 0) ? 8 : 4;   // 256-col tiles in N
  constexpr int GBM = 32 / NBN;              // bm panels per concurrent window
  const int xcd   = blockIdx.x & 7;
  const int slot  = blockIdx.x >> 3;
  const int local = slot & 31;
  const int wrnd  = slot >> 5;
  const int bm = (xcd * 16 + wrnd * GBM + (local & (GBM - 1))) * 256;
  const int bn = (local / GBM) * 256;

  // staging source: pre-swizzled k-slot (rule 21: LDS dest linear)
  const int r0  = tid >> 2;
  const int scl = ((tid & 3) ^ ((r0 >> 1) & 3)) << 4;
  const char* pA = (const char*)A  + (size_t)(bm + r0) * 2048 + scl;
  const char* pB = (const char*)Bw + (size_t)(bn + r0) * 2048 + scl;
  const int dst16 = tid * 16;

  f32x4 acc[8][4] = {};
  short8 aq[4], bq[4];

  auto stgA = [&](int T, int kk, int buf) {
    const char* s = pA + T * 128 + kk * 64;
    char* d = ldsb + buf * 32768 + kk * 16384 + dst16;
    GLOAD16(s, d);
    GLOAD16(s + (size_t)128 * 2048, d + 8192);
  };
  auto stgB = [&](int T, int kk, int buf) {
    const char* s = pB + T * 128 + kk * 64;
    char* d = ldsb + 65536 + buf * 32768 + kk * 16384 + dst16;
    GLOAD16(s, d);
    GLOAD16(s + (size_t)128 * 2048, d + 8192);
  };
  auto ldA4 = [&](const char* LA, int kk, int ih) {
    const char* base = LA + kk * 16384 + (wm * 128 + ih * 64 + frow) * 64 + xsw;
    aq[0] = *(const short8*)(base);
    aq[1] = *(const short8*)(base + 1024);
    aq[2] = *(const short8*)(base + 2048);
    aq[3] = *(const short8*)(base + 3072);
  };
  auto ldB4 = [&](const char* LB, int kk) {
    const char* base = LB + kk * 16384 + (wn * 64 + frow) * 64 + xsw;
    bq[0] = *(const short8*)(base);
    bq[1] = *(const short8*)(base + 1024);
    bq[2] = *(const short8*)(base + 2048);
    bq[3] = *(const short8*)(base + 3072);
  };
  auto mfma16 = [&](int ih) {
    __builtin_amdgcn_s_setprio(1);
    #pragma unroll
    for (int i2 = 0; i2 < 4; ++i2) {
      #pragma unroll
      for (int j = 0; j < 4; ++j)
        acc[ih * 4 + i2][j] =
          __builtin_amdgcn_mfma_f32_16x16x32_bf16(aq[i2], bq[j], acc[ih * 4 + i2][j], 0, 0, 0);
    }
    __builtin_amdgcn_s_setprio(0);
  };

  // prologue: chunks C0..C5 (C_n, n=4T+q; q:0=Akk0,1=Bkk0,2=Akk1,3=Bkk1)
  stgA(0, 0, 0); stgB(0, 0, 0);
  stgA(0, 1, 0); stgB(0, 1, 0);
  stgA(1, 0, 1); stgB(1, 0, 1);
  asm volatile("s_waitcnt vmcnt(8)" ::: "memory");   // C0,C1 resident
  __builtin_amdgcn_s_barrier();

  for (int t = 0; t < 16; ++t) {
    const int buf = t & 1;
    const char* LA = ldsb + buf * 32768;
    const char* LB = ldsb + 65536 + buf * 32768;
    // phase 0: kk0, rows 0-63 of wave-half
    ldB4(LB, 0);
    ldA4(LA, 0, 0);
    if (t < 15) stgA(t + 1, 1, (t + 1) & 1);          // C_{4t+6}
    __builtin_amdgcn_s_barrier();
    asm volatile("s_waitcnt lgkmcnt(0)" ::: "memory");
    mfma16(0);
    __builtin_amdgcn_s_barrier();
    // phase 1: kk0, rows 64-127 (B held in regs)
    ldA4(LA, 0, 1);
    if (t < 15) stgB(t + 1, 1, (t + 1) & 1);          // C_{4t+7}
    if (t < 15) asm volatile("s_waitcnt vmcnt(8)" ::: "memory");   // kk1 ready
    else        asm volatile("s_waitcnt vmcnt(0)" ::: "memory");
    __builtin_amdgcn_s_barrier();
    asm volatile("s_waitcnt lgkmcnt(0)" ::: "memory");
    mfma16(1);
    __builtin_amdgcn_s_barrier();
    // phase 2: kk1, rows 0-63
    ldB4(LB, 1);
    ldA4(LA, 1, 0);
    if (t < 14) stgA(t + 2, 0, buf);                  // C_{4t+8}: this buf's dead kk0
    __builtin_amdgcn_s_barrier();
    asm volatile("s_waitcnt lgkmcnt(0)" ::: "memory");
    mfma16(0);
    __builtin_amdgcn_s_barrier();
    // phase 3: kk1, rows 64-127
    ldA4(LA, 1, 1);
    if (t < 14) stgB(t + 2, 0, buf);                  // C_{4t+9}
    if (t < 14) asm volatile("s_waitcnt vmcnt(8)" ::: "memory");   // next kk0 ready
    else        asm volatile("s_waitcnt vmcnt(4)" ::: "memory");
    __builtin_amdgcn_s_barrier();
    asm volatile("s_waitcnt lgkmcnt(0)" ::: "memory");
    mfma16(1);
    __builtin_amdgcn_s_barrier();
  }

  // epilogue: C/D mapping col=lane&15, row=(lane>>4)*4+r
  if constexpr (MODE == 0) {
    const int plane = bn >> 10;                 // 0: zf, 1: zi (block-uniform)
    const int cb    = bn & 1023;
    unsigned short* ob = plane ? ob1 : ob0;
    const float* bs    = plane ? bias1 : bias0;
    float bv[4];
    #pragma unroll
    for (int j = 0; j < 4; ++j) bv[j] = bs[cb + wn * 64 + j * 16 + frow];
    #pragma unroll
    for (int ii = 0; ii < 8; ++ii) {
      int row = bm + wm * 128 + ii * 16 + ks * 4;
      #pragma unroll
      for (int j = 0; j < 4; ++j) {
        int col = cb + wn * 64 + j * 16 + frow;
        #pragma unroll
        for (int r = 0; r < 4; ++r)
          ob[(size_t)(row + r) * D_ + col] = f2bf(acc[ii][j][r] + bv[j]);
      }
    }
  } else {
    float bv[4];
    #pragma unroll
    for (int j = 0; j < 4; ++j) bv[j] = bias0[bn + wn * 64 + j * 16 + frow];
    #pragma unroll
    for (int ii = 0; ii < 8; ++ii) {
      int row = bm + wm * 128 + ii * 16 + ks * 4;
      #pragma unroll
      for (int j = 0; j < 4; ++j) {
        int col = bn + wn * 64 + j * 16 + frow;
        #pragma unroll
        for (int r = 0; r < 4; ++r)
          of[(size_t)(row + r) * D_ + col] = acc[ii][j][r] + bv[j];
      }
    }
  }
}

// ---------------------------------------------------------------------------
// Gate transform from raw z values
// ---------------------------------------------------------------------------
static __device__ __forceinline__ void gate1(float zf, float zi, float lin,
                                             float& f, float& inp)
{
  float rem = lin / (1.0f + __expf(-zf));
  float ez  = __expf(2.0f * zi);
  float th  = 1.0f - 2.0f / (ez + 1.0f);
  f = 1.0f - rem;
  inp = th * rem;
}

// ---------------------------------------------------------------------------
// Chunked parallel scan, bf16 z inputs, 4 channels/thread.
// grid: B_*CHUNKS blocks x 256 threads
// ---------------------------------------------------------------------------
__global__ __launch_bounds__(256)
void scan_partial_b(const unsigned short* __restrict__ zf,
                    const unsigned short* __restrict__ zi,
                    float* __restrict__ Ag, float* __restrict__ Ug)
{
  int blk = blockIdx.x;
  int b = blk >> 7, c = blk & (CHUNKS - 1);
  int e = threadIdx.x << 2;
  float lin0 = (float)e * (1.0f / 1023.0f);
  size_t base = ((size_t)b * L_ + (size_t)c * TCH) * D_ + e;
  f32x4 a = {1.f,1.f,1.f,1.f}, u = {0.f,0.f,0.f,0.f};
  for (int t = 0; t < TCH; ++t) {
    ushort4v f4 = *(const ushort4v*)(zf + base + (size_t)t * D_);
    ushort4v i4 = *(const ushort4v*)(zi + base + (size_t)t * D_);
    #pragma unroll
    for (int j = 0; j < 4; ++j) {
      float fg, inp;
      gate1(bf2f(f4[j]), bf2f(i4[j]), lin0 + (float)j * (1.0f/1023.0f), fg, inp);
      u[j] = fmaf(fg, u[j], inp);
      a[j] *= fg;
    }
  }
  size_t o = (size_t)(b * CHUNKS + c) * D_ + e;
  *(f32x4*)(Ag + o) = a;
  *(f32x4*)(Ug + o) = u;
}

__global__ __launch_bounds__(256)
void scan_carry(const float* __restrict__ Ag, const float* __restrict__ Ug,
                const float* __restrict__ hidden, float* __restrict__ Hin)
{
  int gid = blockIdx.x * 256 + threadIdx.x;  // B_*D_/4 threads
  int b = gid >> 8;
  int e = (gid & 255) << 2;
  f32x4 h = *(const f32x4*)(hidden + (size_t)b * D_ + e);
  for (int c = 0; c < CHUNKS; ++c) {
    size_t o = (size_t)(b * CHUNKS + c) * D_ + e;
    *(f32x4*)(Hin + o) = h;
    f32x4 A = *(const f32x4*)(Ag + o);
    f32x4 U = *(const f32x4*)(Ug + o);
    h = A * h + U;
  }
}

__global__ __launch_bounds__(256)
void scan_apply_b(const unsigned short* __restrict__ zf,
                  const unsigned short* __restrict__ zi,
                  const float* __restrict__ Hin,
                  float* __restrict__ hout, unsigned short* __restrict__ hb)
{
  int blk = blockIdx.x;
  int b = blk >> 7, c = blk & (CHUNKS - 1);
  int e = threadIdx.x << 2;
  float lin0 = (float)e * (1.0f / 1023.0f);
  size_t base = ((size_t)b * L_ + (size_t)c * TCH) * D_ + e;
  f32x4 h = *(const f32x4*)(Hin + (size_t)(b * CHUNKS + c) * D_ + e);
  for (int t = 0; t < TCH; ++t) {
    size_t o = base + (size_t)t * D_;
    ushort4v f4 = *(const ushort4v*)(zf + o);
    ushort4v i4 = *(const ushort4v*)(zi + o);
    #pragma unroll
    for (int j = 0; j < 4; ++j) {
      float fg, inp;
      gate1(bf2f(f4[j]), bf2f(i4[j]), lin0 + (float)j * (1.0f/1023.0f), fg, inp);
      h[j] = fmaf(fg, h[j], inp);
    }
    *(f32x4*)(hout + o) = h;
    ushort4v p;
    p[0] = f2bf(h[0]); p[1] = f2bf(h[1]); p[2] = f2bf(h[2]); p[3] = f2bf(h[3]);
    *(ushort4v*)(hb + o) = p;
  }
}

// ---------------------------------------------------------------------------
// Slow fallback (fp32 in) — only if ws too small (never expected).
// ---------------------------------------------------------------------------
template<int MODE>
__global__ __launch_bounds__(256, 2)
void gemm_slow(const float* __restrict__ A, const float* __restrict__ B0,
               const float* __restrict__ B1, const float* __restrict__ bias0,
               const float* __restrict__ bias1, float* __restrict__ out0,
               float* __restrict__ out1)
{
  constexpr int BK = 32;
  __shared__ unsigned short As[128 * BK];
  __shared__ unsigned short Bs0[128 * BK];
  __shared__ unsigned short Bs1[(MODE == 0) ? (128 * BK) : 8];

  const int tid = threadIdx.x, lane = tid & 63, wave = tid >> 6;
  const int wr = wave >> 1, wc = wave & 1;
  const int bm = blockIdx.x * 128, bn = blockIdx.y * 128;
  f32x4 acc0[4][4] = {};
  f32x4 acc1[(MODE == 0) ? 4 : 1][(MODE == 0) ? 4 : 1] = {};
  const int frow = lane & 15, kslot = lane >> 4;
  const int xs = kslot ^ (frow & 3);

  auto stage = [&](const float* src, unsigned short* dst) {
    #pragma unroll
    for (int p = 0; p < 4; ++p) {
      int g = p * 256 + tid;
      int row = g >> 3, kq = (g & 7) << 2;
      f32x4 v = *(const f32x4*)(src + (size_t)row * D_ + kq);
      ushort4v w;
      w[0] = f2bf(v[0]); w[1] = f2bf(v[1]); w[2] = f2bf(v[2]); w[3] = f2bf(v[3]);
      int byte = kq << 1, slot = byte >> 4, sub = byte & 15;
      int off = row * 64 + ((slot ^ (row & 3)) << 4) + sub;
      *(ushort4v*)((char*)dst + off) = w;
    }
  };

  for (int k0 = 0; k0 < D_; k0 += BK) {
    stage(A + (size_t)bm * D_ + k0, As);
    stage(B0 + (size_t)bn * D_ + k0, Bs0);
    if constexpr (MODE == 0) stage(B1 + (size_t)bn * D_ + k0, Bs1);
    __syncthreads();
    short8 af[4], bf0[4], bf1[4];
    #pragma unroll
    for (int i = 0; i < 4; ++i) {
      int ar = wr * 64 + i * 16 + frow;
      af[i] = *(const short8*)((const char*)As + ar * 64 + (xs << 4));
      int br = wc * 64 + i * 16 + frow;
      bf0[i] = *(const short8*)((const char*)Bs0 + br * 64 + (xs << 4));
      if constexpr (MODE == 0)
        bf1[i] = *(const short8*)((const char*)Bs1 + br * 64 + (xs << 4));
    }
    #pragma unroll
    for (int i = 0; i < 4; ++i)
      #pragma unroll
      for (int j = 0; j < 4; ++j) {
        acc0[i][j] = __builtin_amdgcn_mfma_f32_16x16x32_bf16(af[i], bf0[j], acc0[i][j], 0, 0, 0);
        if constexpr (MODE == 0)
          acc1[i][j] = __builtin_amdgcn_mfma_f32_16x16x32_bf16(af[i], bf1[j], acc1[i][j], 0, 0, 0);
      }
    __syncthreads();
  }
  #pragma unroll
  for (int i = 0; i < 4; ++i)
    #pragma unroll
    for (int j = 0; j < 4; ++j)
      #pragma unroll
      for (int r = 0; r < 4; ++r) {
        int row = bm + wr * 64 + i * 16 + (lane >> 4) * 4 + r;
        int col = bn + wc * 64 + j * 16 + (lane & 15);
        size_t idx = (size_t)row * D_ + col;
        if constexpr (MODE == 0) {
          float zf = acc0[i][j][r] + bias0[col];
          float linv = (float)col * (1.0f / 1023.0f);
          float rem = linv / (1.0f + __expf(-zf));
          float zi = acc1[i][j][r] + bias1[col];
          float e2 = __expf(2.0f * zi);
          float th = 1.0f - 2.0f / (e2 + 1.0f);
          out0[idx] = 1.0f - rem;
          out1[idx] = th * rem;
        } else {
          out0[idx] = acc0[i][j][r] + bias0[col];
        }
      }
}

__global__ __launch_bounds__(256)
void scan_partial_f(const float* __restrict__ p0, const float* __restrict__ p1,
                    float* __restrict__ Ag, float* __restrict__ Ug)
{
  int blk = blockIdx.x;                      // B_*CHUNKS*2 blocks
  int b = blk / (CHUNKS * 2);
  int c = (blk >> 1) & (CHUNKS - 1);
  int e = ((blk & 1) << 9) + threadIdx.x * 2;
  size_t base = ((size_t)b * L_ + (size_t)c * TCH) * D_ + e;
  f32x2 a = {1.0f, 1.0f}, u = {0.0f, 0.0f};
  for (int t = 0; t < TCH; ++t) {
    f32x2 f = *(const f32x2*)(p0 + base + (size_t)t * D_);
    f32x2 i = *(const f32x2*)(p1 + base + (size_t)t * D_);
    u = f * u + i;
    a = a * f;
  }
  size_t o = (size_t)(b * CHUNKS + c) * D_ + e;
  *(f32x2*)(Ag + o) = a;
  *(f32x2*)(Ug + o) = u;
}

__global__ __launch_bounds__(256)
void scan_apply_f(const float* __restrict__ p0, float* __restrict__ p1_io,
                  const float* __restrict__ Hin)
{
  int blk = blockIdx.x;
  int b = blk / (CHUNKS * 2);
  int c = (blk >> 1) & (CHUNKS - 1);
  int e = ((blk & 1) << 9) + threadIdx.x * 2;
  size_t base = ((size_t)b * L_ + (size_t)c * TCH) * D_ + e;
  f32x2 h = *(const f32x2*)(Hin + (size_t)(b * CHUNKS + c) * D_ + e);
  for (int t = 0; t < TCH; ++t) {
    size_t o = base + (size_t)t * D_;
    f32x2 f = *(const f32x2*)(p0 + o);
    f32x2 i = *(const f32x2*)(p1_io + o);
    h = f * h + i;
    *(f32x2*)(p1_io + o) = h;
  }
}

// ---------------------------------------------------------------------------
extern "C" void kernel_launch(void* const* d_in, const int* in_sizes, int n_in,
                              void* d_out, int out_size, void* d_ws, size_t ws_size,
                              hipStream_t stream)
{
  const float* x      = (const float*)d_in[0];
  const float* hidden = (const float*)d_in[1];
  const float* W_f    = (const float*)d_in[2];
  const float* b_f    = (const float*)d_in[3];
  const float* W_i    = (const float*)d_in[4];
  const float* b_i    = (const float*)d_in[5];
  const float* W_o    = (const float*)d_in[6];
  const float* b_o    = (const float*)d_in[7];

  float* y = (float*)d_out;
  float* h = y + (size_t)M_ * D_;

  const size_t xb_elems = (size_t)M_ * D_;
  const size_t w_elems  = (size_t)D_ * D_;
  const size_t agg      = (size_t)B_ * CHUNKS * D_;
  const size_t need = (xb_elems * 3 + 3 * w_elems) * 2 + agg * 3 * 4;

  if (ws_size >= need) {
    unsigned short* xb  = (unsigned short*)d_ws;       // bf16 x, later bf16 h
    unsigned short* wfb = xb + xb_elems;               // [W_f;W_i] stacked 2048x1024
    unsigned short* wib = wfb + w_elems;
    unsigned short* wob = wib + w_elems;
    unsigned short* zfb = wob + w_elems;               // bf16 zf
    unsigned short* zib = zfb + xb_elems;              // bf16 zi
    float* Ag  = (float*)(zib + xb_elems);
    float* Ug  = Ag + agg;
    float* Hin = Ug + agg;

    cvt_bf16<<<(int)(xb_elems / 8 / 256), 256, 0, stream>>>(x, xb, (int)(xb_elems / 8));
    cvt_w3<<<3 * (int)(w_elems / 8 / 256), 256, 0, stream>>>(W_f, W_i, W_o, wfb);

    // stacked gate GEMM: N = 2048 -> 1024 blocks
    gemm256<0><<<1024, 512, 0, stream>>>(xb, wfb, b_f, b_i, zfb, zib, nullptr);

    int pblocks = B_ * CHUNKS;               // 1024
    scan_partial_b<<<pblocks, 256, 0, stream>>>(zfb, zib, Ag, Ug);
    scan_carry<<<(B_ * D_ / 4) / 256, 256, 0, stream>>>(Ag, Ug, hidden, Hin);
    scan_apply_b<<<pblocks, 256, 0, stream>>>(zfb, zib, Hin, h, xb); // h fp32 + bf16

    gemm256<1><<<512, 512, 0, stream>>>(xb, wob, b_o, nullptr, nullptr, nullptr, y);
  } else {
    float* Ag  = (float*)d_ws;
    float* Ug  = Ag + agg;
    float* Hin = Ug + agg;
    dim3 gg(M_ / 128, D_ / 128);
    int pblocks = B_ * CHUNKS * 2;

    gemm_slow<0><<<gg, 256, 0, stream>>>(x, W_f, W_i, b_f, b_i, y, h);
    scan_partial_f<<<pblocks, 256, 0, stream>>>(y, h, Ag, Ug);
    scan_carry<<<(B_ * D_ / 4) / 256, 256, 0, stream>>>(Ag, Ug, hidden, Hin);
    scan_apply_f<<<pblocks, 256, 0, stream>>>(y, h, Hin);
    gemm_slow<1><<<gg, 256, 0, stream>>>(h, W_o, nullptr, b_o, nullptr, y, nullptr);
  }
}

// Round 8
// 388.656 us; speedup vs baseline: 3.0510x; 1.0059x over previous
//
#include <hip/hip_runtime.h>
#include <stdint.h>

#define B_ 8
#define L_ 4096
#define D_ 1024
#define M_ (B_*L_)        // 32768 rows
#define CHUNKS 128
#define TCH (L_/CHUNKS)   // 32

typedef float f32x4 __attribute__((ext_vector_type(4)));
typedef float f32x2 __attribute__((ext_vector_type(2)));
typedef short short8 __attribute__((ext_vector_type(8)));
typedef unsigned short ushort4v __attribute__((ext_vector_type(4)));

static __device__ __forceinline__ unsigned short f2bf(float f) {
  union { float f; unsigned u; } v; v.f = f;
  unsigned r = v.u + 0x7FFFu + ((v.u >> 16) & 1u);   // round-to-nearest-even
  return (unsigned short)(r >> 16);
}
static __device__ __forceinline__ float bf2f(unsigned short u) {
  union { unsigned u; float f; } v; v.u = ((unsigned)u) << 16; return v.f;
}

#define GLOAD16(g, l) \
  __builtin_amdgcn_global_load_lds((__attribute__((address_space(1))) const void*)(g), \
                                   (__attribute__((address_space(3))) void*)(l), 16, 0, 0)

// ---------------------------------------------------------------------------
// fp32 -> bf16 converts
// ---------------------------------------------------------------------------
__global__ __launch_bounds__(256)
void cvt_bf16(const float* __restrict__ src, unsigned short* __restrict__ dst, int n8)
{
  int gid = blockIdx.x * 256 + threadIdx.x;
  if (gid >= n8) return;
  const f32x4* s = (const f32x4*)(src + (size_t)gid * 8);
  f32x4 v0 = s[0], v1 = s[1];
  union { short8 v; unsigned short u[8]; } w;
  w.u[0] = f2bf(v0[0]); w.u[1] = f2bf(v0[1]); w.u[2] = f2bf(v0[2]); w.u[3] = f2bf(v0[3]);
  w.u[4] = f2bf(v1[0]); w.u[5] = f2bf(v1[1]); w.u[6] = f2bf(v1[2]); w.u[7] = f2bf(v1[3]);
  *(short8*)(dst + (size_t)gid * 8) = w.v;
}

__global__ __launch_bounds__(256)
void cvt_w3(const float* __restrict__ w0, const float* __restrict__ w1,
            const float* __restrict__ w2, unsigned short* __restrict__ dst)
{
  const int per = (D_ * D_) / 8 / 256;
  int m = blockIdx.x / per;
  int gid = (blockIdx.x % per) * 256 + threadIdx.x;
  const float* src = (m == 0) ? w0 : (m == 1) ? w1 : w2;
  const f32x4* s = (const f32x4*)(src + (size_t)gid * 8);
  f32x4 v0 = s[0], v1 = s[1];
  union { short8 v; unsigned short u[8]; } w;
  w.u[0] = f2bf(v0[0]); w.u[1] = f2bf(v0[1]); w.u[2] = f2bf(v0[2]); w.u[3] = f2bf(v0[3]);
  w.u[4] = f2bf(v1[0]); w.u[5] = f2bf(v1[1]); w.u[6] = f2bf(v1[2]); w.u[7] = f2bf(v1[3]);
  *(short8*)(dst + (size_t)m * D_ * D_ + (size_t)gid * 8) = w.v;
}

// ---------------------------------------------------------------------------
// 256x256 8-wave GEMM, 4-phase/K-tile, counted vmcnt, fully unrolled K-loop.
// MODE 0: stacked gates Bw=[W_f;W_i] (2048x1024); epilogue writes
//         plane0: rem = lin*sigmoid(zf+b)   (SMALL quantity — bf16-safe;
//                 storing f=1-rem in bf16 blows up error by 1/rem!)
//         plane1: t = tanh(zi+b)
// MODE 1: y = h*W_o^T + b_o, fp32 out.
// A-locality dispatch: 32 co-resident blocks per XCD (1 blk/CU, xcd=idx&7)
// cover {GBM bm panels} x {all bn}, so A is fetched once into that L2.
// ---------------------------------------------------------------------------
template<int MODE>
__global__ __launch_bounds__(512, 2)
void gemm256(const unsigned short* __restrict__ A,
             const unsigned short* __restrict__ Bw,
             const float* __restrict__ bias0,
             const float* __restrict__ bias1,
             unsigned short* __restrict__ ob0,   // rem (MODE 0)
             unsigned short* __restrict__ ob1,   // t   (MODE 0)
             float* __restrict__ of)             // y   (MODE 1)
{
  __shared__ unsigned short lds[65536];   // 128KB: A [2buf][2kk][16KB] | B at +64KB
  char* ldsb = (char*)lds;

  const int tid  = threadIdx.x;
  const int lane = tid & 63;
  const int wid  = tid >> 6;
  const int wm   = wid >> 2;          // 0..1
  const int wn   = wid & 3;           // 0..3
  const int frow = lane & 15, ks = lane >> 4;
  const int xsw  = (ks ^ ((frow >> 1) & 3)) << 4;

  constexpr int NBN = (MODE == 0) ? 8 : 4;
  constexpr int GBM = 32 / NBN;
  const int xcd   = blockIdx.x & 7;
  const int slot  = blockIdx.x >> 3;
  const int local = slot & 31;
  const int wrnd  = slot >> 5;
  const int bm = (xcd * 16 + wrnd * GBM + (local & (GBM - 1))) * 256;
  const int bn = (local / GBM) * 256;

  const int r0  = tid >> 2;
  const int scl = ((tid & 3) ^ ((r0 >> 1) & 3)) << 4;
  const char* pA = (const char*)A  + (size_t)(bm + r0) * 2048 + scl;
  const char* pB = (const char*)Bw + (size_t)(bn + r0) * 2048 + scl;
  const int dst16 = tid * 16;

  f32x4 acc[8][4] = {};
  short8 aq[4], bq[4];

  auto stgA = [&](int T, int kk, int buf) {
    const char* s = pA + T * 128 + kk * 64;
    char* d = ldsb + buf * 32768 + kk * 16384 + dst16;
    GLOAD16(s, d);
    GLOAD16(s + (size_t)128 * 2048, d + 8192);
  };
  auto stgB = [&](int T, int kk, int buf) {
    const char* s = pB + T * 128 + kk * 64;
    char* d = ldsb + 65536 + buf * 32768 + kk * 16384 + dst16;
    GLOAD16(s, d);
    GLOAD16(s + (size_t)128 * 2048, d + 8192);
  };
  // interleaved A/B reads: first MFMA's operands (aq0,bq0) complete earliest
  auto ldAB4 = [&](const char* LA, const char* LB, int kk, int ih) {
    const char* ab = LA + kk * 16384 + (wm * 128 + ih * 64 + frow) * 64 + xsw;
    const char* bb = LB + kk * 16384 + (wn * 64 + frow) * 64 + xsw;
    aq[0] = *(const short8*)(ab);
    bq[0] = *(const short8*)(bb);
    bq[1] = *(const short8*)(bb + 1024);
    bq[2] = *(const short8*)(bb + 2048);
    bq[3] = *(const short8*)(bb + 3072);
    aq[1] = *(const short8*)(ab + 1024);
    aq[2] = *(const short8*)(ab + 2048);
    aq[3] = *(const short8*)(ab + 3072);
  };
  auto ldA4 = [&](const char* LA, int kk, int ih) {
    const char* ab = LA + kk * 16384 + (wm * 128 + ih * 64 + frow) * 64 + xsw;
    aq[0] = *(const short8*)(ab);
    aq[1] = *(const short8*)(ab + 1024);
    aq[2] = *(const short8*)(ab + 2048);
    aq[3] = *(const short8*)(ab + 3072);
  };
  auto mfma16 = [&](int ih) {
    __builtin_amdgcn_s_setprio(1);
    #pragma unroll
    for (int i2 = 0; i2 < 4; ++i2) {
      #pragma unroll
      for (int j = 0; j < 4; ++j)
        acc[ih * 4 + i2][j] =
          __builtin_amdgcn_mfma_f32_16x16x32_bf16(aq[i2], bq[j], acc[ih * 4 + i2][j], 0, 0, 0);
    }
    __builtin_amdgcn_s_setprio(0);
  };

// One K-tile = 4 phases. BUF/stage-flags/vmcnt are compile-time per expansion.
#define DO_TILE(T, BUF, STG1, STG2, W1, W3)                                   \
  {                                                                           \
    const char* LA = ldsb + (BUF) * 32768;                                    \
    const char* LB = ldsb + 65536 + (BUF) * 32768;                            \
    ldAB4(LA, LB, 0, 0);                                                      \
    if (STG1) stgA((T) + 1, 1, ((T) + 1) & 1);                                \
    __builtin_amdgcn_s_barrier();                                             \
    mfma16(0);                                                                \
    __builtin_amdgcn_s_barrier();                                             \
    ldA4(LA, 0, 1);                                                           \
    if (STG1) stgB((T) + 1, 1, ((T) + 1) & 1);                                \
    asm volatile("s_waitcnt vmcnt(" #W1 ")" ::: "memory");                    \
    __builtin_amdgcn_s_barrier();                                             \
    mfma16(1);                                                                \
    __builtin_amdgcn_s_barrier();                                             \
    ldAB4(LA, LB, 1, 0);                                                      \
    if (STG2) stgA((T) + 2, 0, (BUF));                                        \
    __builtin_amdgcn_s_barrier();                                             \
    mfma16(0);                                                                \
    __builtin_amdgcn_s_barrier();                                             \
    ldA4(LA, 1, 1);                                                           \
    if (STG2) stgB((T) + 2, 0, (BUF));                                        \
    asm volatile("s_waitcnt vmcnt(" #W3 ")" ::: "memory");                    \
    __builtin_amdgcn_s_barrier();                                             \
    mfma16(1);                                                                \
    __builtin_amdgcn_s_barrier();                                             \
  }

  // prologue: chunks C0..C5 in order; wait C0,C1 resident
  stgA(0, 0, 0); stgB(0, 0, 0);
  stgA(0, 1, 0); stgB(0, 1, 0);
  stgA(1, 0, 1); stgB(1, 0, 1);
  asm volatile("s_waitcnt vmcnt(8)" ::: "memory");
  __builtin_amdgcn_s_barrier();

  for (int tt = 0; tt < 7; ++tt) {
    int t0 = tt * 2;
    DO_TILE(t0,     0, true, true, 8, 8);
    DO_TILE(t0 + 1, 1, true, true, 8, 8);
  }
  DO_TILE(14, 0, true,  false, 8, 4);
  DO_TILE(15, 1, false, false, 0, 0);
#undef DO_TILE

  // epilogue: C/D mapping col=lane&15, row=(lane>>4)*4+r
  if constexpr (MODE == 0) {
    const int plane = bn >> 10;                 // 0: rem, 1: tanh
    const int cb    = bn & 1023;
    unsigned short* ob = plane ? ob1 : ob0;
    const float* bs    = plane ? bias1 : bias0;
    float bv[4];
    #pragma unroll
    for (int j = 0; j < 4; ++j) bv[j] = bs[cb + wn * 64 + j * 16 + frow];
    #pragma unroll
    for (int ii = 0; ii < 8; ++ii) {
      int row = bm + wm * 128 + ii * 16 + ks * 4;
      #pragma unroll
      for (int j = 0; j < 4; ++j) {
        int col = cb + wn * 64 + j * 16 + frow;
        float lin = (float)col * (1.0f / 1023.0f);
        #pragma unroll
        for (int r = 0; r < 4; ++r) {
          float z = acc[ii][j][r] + bv[j];
          float v;
          if (plane == 0) {
            v = lin / (1.0f + __expf(-z));             // rem (small, bf16-safe)
          } else {
            float e2 = __expf(2.0f * z);
            v = 1.0f - 2.0f / (e2 + 1.0f);             // tanh
          }
          ob[(size_t)(row + r) * D_ + col] = f2bf(v);
        }
      }
    }
  } else {
    float bv[4];
    #pragma unroll
    for (int j = 0; j < 4; ++j) bv[j] = bias0[bn + wn * 64 + j * 16 + frow];
    #pragma unroll
    for (int ii = 0; ii < 8; ++ii) {
      int row = bm + wm * 128 + ii * 16 + ks * 4;
      #pragma unroll
      for (int j = 0; j < 4; ++j) {
        int col = bn + wn * 64 + j * 16 + frow;
        #pragma unroll
        for (int r = 0; r < 4; ++r)
          of[(size_t)(row + r) * D_ + col] = acc[ii][j][r] + bv[j];
      }
    }
  }
}

// ---------------------------------------------------------------------------
// Chunked parallel scan over precomputed (rem, t), 4 channels/thread.
// f = 1 - rem (fp32);  h_t = f*h_{t-1} + t*rem
// ---------------------------------------------------------------------------
__global__ __launch_bounds__(256)
void scan_partial_b(const unsigned short* __restrict__ rb,
                    const unsigned short* __restrict__ tb,
                    float* __restrict__ Ag, float* __restrict__ Ug)
{
  int blk = blockIdx.x;
  int b = blk >> 7, c = blk & (CHUNKS - 1);
  int e = threadIdx.x << 2;
  size_t base = ((size_t)b * L_ + (size_t)c * TCH) * D_ + e;
  f32x4 a = {1.f,1.f,1.f,1.f}, u = {0.f,0.f,0.f,0.f};
  for (int t = 0; t < TCH; ++t) {
    ushort4v r4 = *(const ushort4v*)(rb + base + (size_t)t * D_);
    ushort4v t4 = *(const ushort4v*)(tb + base + (size_t)t * D_);
    #pragma unroll
    for (int j = 0; j < 4; ++j) {
      float rem = bf2f(r4[j]);
      float f   = 1.0f - rem;
      float inp = bf2f(t4[j]) * rem;
      u[j] = fmaf(f, u[j], inp);
      a[j] *= f;
    }
  }
  size_t o = (size_t)(b * CHUNKS + c) * D_ + e;
  *(f32x4*)(Ag + o) = a;
  *(f32x4*)(Ug + o) = u;
}

__global__ __launch_bounds__(256)
void scan_carry(const float* __restrict__ Ag, const float* __restrict__ Ug,
                const float* __restrict__ hidden, float* __restrict__ Hin)
{
  int gid = blockIdx.x * 256 + threadIdx.x;  // B_*D_/4 threads
  int b = gid >> 8;
  int e = (gid & 255) << 2;
  f32x4 h = *(const f32x4*)(hidden + (size_t)b * D_ + e);
  for (int c = 0; c < CHUNKS; ++c) {
    size_t o = (size_t)(b * CHUNKS + c) * D_ + e;
    *(f32x4*)(Hin + o) = h;
    f32x4 A = *(const f32x4*)(Ag + o);
    f32x4 U = *(const f32x4*)(Ug + o);
    h = A * h + U;
  }
}

__global__ __launch_bounds__(256)
void scan_apply_b(const unsigned short* __restrict__ rb,
                  const unsigned short* __restrict__ tb,
                  const float* __restrict__ Hin,
                  float* __restrict__ hout, unsigned short* __restrict__ hb)
{
  int blk = blockIdx.x;
  int b = blk >> 7, c = blk & (CHUNKS - 1);
  int e = threadIdx.x << 2;
  size_t base = ((size_t)b * L_ + (size_t)c * TCH) * D_ + e;
  f32x4 h = *(const f32x4*)(Hin + (size_t)(b * CHUNKS + c) * D_ + e);
  for (int t = 0; t < TCH; ++t) {
    size_t o = base + (size_t)t * D_;
    ushort4v r4 = *(const ushort4v*)(rb + o);
    ushort4v t4 = *(const ushort4v*)(tb + o);
    #pragma unroll
    for (int j = 0; j < 4; ++j) {
      float rem = bf2f(r4[j]);
      float f   = 1.0f - rem;
      float inp = bf2f(t4[j]) * rem;
      h[j] = fmaf(f, h[j], inp);
    }
    *(f32x4*)(hout + o) = h;
    ushort4v p;
    p[0] = f2bf(h[0]); p[1] = f2bf(h[1]); p[2] = f2bf(h[2]); p[3] = f2bf(h[3]);
    *(ushort4v*)(hb + o) = p;
  }
}

// ---------------------------------------------------------------------------
// Slow fallback (fp32 in) — only if ws too small (never expected).
// ---------------------------------------------------------------------------
template<int MODE>
__global__ __launch_bounds__(256, 2)
void gemm_slow(const float* __restrict__ A, const float* __restrict__ B0,
               const float* __restrict__ B1, const float* __restrict__ bias0,
               const float* __restrict__ bias1, float* __restrict__ out0,
               float* __restrict__ out1)
{
  constexpr int BK = 32;
  __shared__ unsigned short As[128 * BK];
  __shared__ unsigned short Bs0[128 * BK];
  __shared__ unsigned short Bs1[(MODE == 0) ? (128 * BK) : 8];

  const int tid = threadIdx.x, lane = tid & 63, wave = tid >> 6;
  const int wr = wave >> 1, wc = wave & 1;
  const int bm = blockIdx.x * 128, bn = blockIdx.y * 128;
  f32x4 acc0[4][4] = {};
  f32x4 acc1[(MODE == 0) ? 4 : 1][(MODE == 0) ? 4 : 1] = {};
  const int frow = lane & 15, kslot = lane >> 4;
  const int xs = kslot ^ (frow & 3);

  auto stage = [&](const float* src, unsigned short* dst) {
    #pragma unroll
    for (int p = 0; p < 4; ++p) {
      int g = p * 256 + tid;
      int row = g >> 3, kq = (g & 7) << 2;
      f32x4 v = *(const f32x4*)(src + (size_t)row * D_ + kq);
      ushort4v w;
      w[0] = f2bf(v[0]); w[1] = f2bf(v[1]); w[2] = f2bf(v[2]); w[3] = f2bf(v[3]);
      int byte = kq << 1, slot = byte >> 4, sub = byte & 15;
      int off = row * 64 + ((slot ^ (row & 3)) << 4) + sub;
      *(ushort4v*)((char*)dst + off) = w;
    }
  };

  for (int k0 = 0; k0 < D_; k0 += BK) {
    stage(A + (size_t)bm * D_ + k0, As);
    stage(B0 + (size_t)bn * D_ + k0, Bs0);
    if constexpr (MODE == 0) stage(B1 + (size_t)bn * D_ + k0, Bs1);
    __syncthreads();
    short8 af[4], bf0[4], bf1[4];
    #pragma unroll
    for (int i = 0; i < 4; ++i) {
      int ar = wr * 64 + i * 16 + frow;
      af[i] = *(const short8*)((const char*)As + ar * 64 + (xs << 4));
      int br = wc * 64 + i * 16 + frow;
      bf0[i] = *(const short8*)((const char*)Bs0 + br * 64 + (xs << 4));
      if constexpr (MODE == 0)
        bf1[i] = *(const short8*)((const char*)Bs1 + br * 64 + (xs << 4));
    }
    #pragma unroll
    for (int i = 0; i < 4; ++i)
      #pragma unroll
      for (int j = 0; j < 4; ++j) {
        acc0[i][j] = __builtin_amdgcn_mfma_f32_16x16x32_bf16(af[i], bf0[j], acc0[i][j], 0, 0, 0);
        if constexpr (MODE == 0)
          acc1[i][j] = __builtin_amdgcn_mfma_f32_16x16x32_bf16(af[i], bf1[j], acc1[i][j], 0, 0, 0);
      }
    __syncthreads();
  }
  #pragma unroll
  for (int i = 0; i < 4; ++i)
    #pragma unroll
    for (int j = 0; j < 4; ++j)
      #pragma unroll
      for (int r = 0; r < 4; ++r) {
        int row = bm + wr * 64 + i * 16 + (lane >> 4) * 4 + r;
        int col = bn + wc * 64 + j * 16 + (lane & 15);
        size_t idx = (size_t)row * D_ + col;
        if constexpr (MODE == 0) {
          float zf = acc0[i][j][r] + bias0[col];
          float linv = (float)col * (1.0f / 1023.0f);
          float rem = linv / (1.0f + __expf(-zf));
          float zi = acc1[i][j][r] + bias1[col];
          float e2 = __expf(2.0f * zi);
          float th = 1.0f - 2.0f / (e2 + 1.0f);
          out0[idx] = 1.0f - rem;
          out1[idx] = th * rem;
        } else {
          out0[idx] = acc0[i][j][r] + bias0[col];
        }
      }
}

__global__ __launch_bounds__(256)
void scan_partial_f(const float* __restrict__ p0, const float* __restrict__ p1,
                    float* __restrict__ Ag, float* __restrict__ Ug)
{
  int blk = blockIdx.x;
  int b = blk / (CHUNKS * 2);
  int c = (blk >> 1) & (CHUNKS - 1);
  int e = ((blk & 1) << 9) + threadIdx.x * 2;
  size_t base = ((size_t)b * L_ + (size_t)c * TCH) * D_ + e;
  f32x2 a = {1.0f, 1.0f}, u = {0.0f, 0.0f};
  for (int t = 0; t < TCH; ++t) {
    f32x2 f = *(const f32x2*)(p0 + base + (size_t)t * D_);
    f32x2 i = *(const f32x2*)(p1 + base + (size_t)t * D_);
    u = f * u + i;
    a = a * f;
  }
  size_t o = (size_t)(b * CHUNKS + c) * D_ + e;
  *(f32x2*)(Ag + o) = a;
  *(f32x2*)(Ug + o) = u;
}

__global__ __launch_bounds__(256)
void scan_apply_f(const float* __restrict__ p0, float* __restrict__ p1_io,
                  const float* __restrict__ Hin)
{
  int blk = blockIdx.x;
  int b = blk / (CHUNKS * 2);
  int c = (blk >> 1) & (CHUNKS - 1);
  int e = ((blk & 1) << 9) + threadIdx.x * 2;
  size_t base = ((size_t)b * L_ + (size_t)c * TCH) * D_ + e;
  f32x2 h = *(const f32x2*)(Hin + (size_t)(b * CHUNKS + c) * D_ + e);
  for (int t = 0; t < TCH; ++t) {
    size_t o = base + (size_t)t * D_;
    f32x2 f = *(const f32x2*)(p0 + o);
    f32x2 i = *(const f32x2*)(p1_io + o);
    h = f * h + i;
    *(f32x2*)(p1_io + o) = h;
  }
}

// ---------------------------------------------------------------------------
extern "C" void kernel_launch(void* const* d_in, const int* in_sizes, int n_in,
                              void* d_out, int out_size, void* d_ws, size_t ws_size,
                              hipStream_t stream)
{
  const float* x      = (const float*)d_in[0];
  const float* hidden = (const float*)d_in[1];
  const float* W_f    = (const float*)d_in[2];
  const float* b_f    = (const float*)d_in[3];
  const float* W_i    = (const float*)d_in[4];
  const float* b_i    = (const float*)d_in[5];
  const float* W_o    = (const float*)d_in[6];
  const float* b_o    = (const float*)d_in[7];

  float* y = (float*)d_out;
  float* h = y + (size_t)M_ * D_;

  const size_t xb_elems = (size_t)M_ * D_;
  const size_t w_elems  = (size_t)D_ * D_;
  const size_t agg      = (size_t)B_ * CHUNKS * D_;
  const size_t need = (xb_elems * 3 + 3 * w_elems) * 2 + agg * 3 * 4;

  if (ws_size >= need) {
    unsigned short* xb  = (unsigned short*)d_ws;       // bf16 x, later bf16 h
    unsigned short* wfb = xb + xb_elems;               // [W_f;W_i] stacked
    unsigned short* wib = wfb + w_elems;
    unsigned short* wob = wib + w_elems;
    unsigned short* rbv = wob + w_elems;               // bf16 rem
    unsigned short* tbv = rbv + xb_elems;              // bf16 tanh
    float* Ag  = (float*)(tbv + xb_elems);
    float* Ug  = Ag + agg;
    float* Hin = Ug + agg;

    cvt_bf16<<<(int)(xb_elems / 8 / 256), 256, 0, stream>>>(x, xb, (int)(xb_elems / 8));
    cvt_w3<<<3 * (int)(w_elems / 8 / 256), 256, 0, stream>>>(W_f, W_i, W_o, wfb);

    gemm256<0><<<1024, 512, 0, stream>>>(xb, wfb, b_f, b_i, rbv, tbv, nullptr);

    int pblocks = B_ * CHUNKS;               // 1024
    scan_partial_b<<<pblocks, 256, 0, stream>>>(rbv, tbv, Ag, Ug);
    scan_carry<<<(B_ * D_ / 4) / 256, 256, 0, stream>>>(Ag, Ug, hidden, Hin);
    scan_apply_b<<<pblocks, 256, 0, stream>>>(rbv, tbv, Hin, h, xb);

    gemm256<1><<<512, 512, 0, stream>>>(xb, wob, b_o, nullptr, nullptr, nullptr, y);
  } else {
    float* Ag  = (float*)d_ws;
    float* Ug  = Ag + agg;
    float* Hin = Ug + agg;
    dim3 gg(M_ / 128, D_ / 128);
    int pblocks = B_ * CHUNKS * 2;

    gemm_slow<0><<<gg, 256, 0, stream>>>(x, W_f, W_i, b_f, b_i, y, h);
    scan_partial_f<<<pblocks, 256, 0, stream>>>(y, h, Ag, Ug);
    scan_carry<<<(B_ * D_ / 4) / 256, 256, 0, stream>>>(Ag, Ug, hidden, Hin);
    scan_apply_f<<<pblocks, 256, 0, stream>>>(y, h, Hin);
    gemm_slow<1><<<gg, 256, 0, stream>>>(h, W_o, nullptr, b_o, nullptr, y, nullptr);
  }
}